// Round 9
// baseline (733.888 us; speedup 1.0000x reference)
//
#include <hip/hip_runtime.h>
#include <hip/hip_bf16.h>
#include <math.h>

#define BB   64
#define NN   64
#define HH   128
#define OBS_ 128
#define AA   16
#define BN_  4096
#define NM   63
#define G3   384
#define G4   512
#define LDSW 136   // ushorts/row

typedef _Float16 f16x8 __attribute__((ext_vector_type(8)));
typedef float    f32x4 __attribute__((ext_vector_type(4)));

__device__ __forceinline__ float sigf(float x) { return 1.0f / (1.0f + expf(-x)); }

// fast device transcendentals (v_exp_f32 / v_rcp_f32, ~2-3 ulp)
__device__ __forceinline__ float fsig(float x) {
    return __builtin_amdgcn_rcpf(1.0f + __builtin_amdgcn_exp2f(-1.4426950408889634f * x));
}
__device__ __forceinline__ float ftanh(float x) {
    return 1.0f - 2.0f * __builtin_amdgcn_rcpf(1.0f + __builtin_amdgcn_exp2f(2.8853900817779268f * x));
}

__device__ __forceinline__ unsigned short h2u(_Float16 h) {
    union { _Float16 f; unsigned short u; } cv; cv.f = h; return cv.u;
}

// ---- generic C = A@B^T (+ A2@B2^T) (+bias)(+relu)(+row-mask on A2), tile 64x64 ----
template<bool DUAL, bool RELU, bool BIAS, bool RMASK>
__global__ __launch_bounds__(256)
void gemm_tn(const float* __restrict__ A, int lda,
             const float* __restrict__ B, int ldb,
             const float* __restrict__ A2, int lda2,
             const float* __restrict__ B2, int ldb2,
             const float* __restrict__ bias,
             const float* __restrict__ rmask,
             float* __restrict__ C, int ldc, int K)
{
    __shared__ float As[32][68];
    __shared__ float Bs[32][68];
    const int t = threadIdx.x;
    const int tx = t & 15, ty = t >> 4;
    const int row0 = blockIdx.y * 64, col0 = blockIdx.x * 64;
    const int lm = t >> 2;           // 0..63
    const int lk = (t & 3) * 8;      // 0,8,16,24
    float acc[4][4] = {};
    const int npass = DUAL ? 2 : 1;
    for (int pass = 0; pass < npass; ++pass) {
        const float* Ap = pass ? A2 : A; const int ldap = pass ? lda2 : lda;
        const float* Bp = pass ? B2 : B; const int ldbp = pass ? ldb2 : ldb;
        for (int k0 = 0; k0 < K; k0 += 32) {
            __syncthreads();
            {
                const float* srcA = Ap + (size_t)(row0 + lm) * ldap + k0 + lk;
                float4 a0 = *(const float4*)(srcA);
                float4 a1 = *(const float4*)(srcA + 4);
                if (RMASK && pass == 1) {
                    const float mk = rmask[row0 + lm];
                    a0.x *= mk; a0.y *= mk; a0.z *= mk; a0.w *= mk;
                    a1.x *= mk; a1.y *= mk; a1.z *= mk; a1.w *= mk;
                }
                As[lk + 0][lm] = a0.x; As[lk + 1][lm] = a0.y; As[lk + 2][lm] = a0.z; As[lk + 3][lm] = a0.w;
                As[lk + 4][lm] = a1.x; As[lk + 5][lm] = a1.y; As[lk + 6][lm] = a1.z; As[lk + 7][lm] = a1.w;
                const float* srcB = Bp + (size_t)(col0 + lm) * ldbp + k0 + lk;
                float4 b0 = *(const float4*)(srcB);
                float4 b1 = *(const float4*)(srcB + 4);
                Bs[lk + 0][lm] = b0.x; Bs[lk + 1][lm] = b0.y; Bs[lk + 2][lm] = b0.z; Bs[lk + 3][lm] = b0.w;
                Bs[lk + 4][lm] = b1.x; Bs[lk + 5][lm] = b1.y; Bs[lk + 6][lm] = b1.z; Bs[lk + 7][lm] = b1.w;
            }
            __syncthreads();
            #pragma unroll
            for (int k = 0; k < 32; ++k) {
                float av[4], bv[4];
                *(float4*)av = *(const float4*)&As[k][ty * 4];
                *(float4*)bv = *(const float4*)&Bs[k][tx * 4];
                #pragma unroll
                for (int i = 0; i < 4; ++i)
                    #pragma unroll
                    for (int j = 0; j < 4; ++j)
                        acc[i][j] = fmaf(av[i], bv[j], acc[i][j]);
            }
        }
    }
    #pragma unroll
    for (int i = 0; i < 4; ++i) {
        const int r = row0 + ty * 4 + i;
        const int c = col0 + tx * 4;
        float vv[4];
        #pragma unroll
        for (int j = 0; j < 4; ++j) {
            float x = acc[i][j];
            if (BIAS) x += bias[c + j];
            if (RELU) x = fmaxf(x, 0.0f);
            vv[j] = x;
        }
        *(float4*)&C[(size_t)r * ldc + c] = *(float4*)vv;
    }
}

__global__ void lstm_pointwise(const float* __restrict__ gates,
                               const float* __restrict__ bih, const float* __restrict__ bhh,
                               const float* __restrict__ lstm_c, const float* __restrict__ masks,
                               float* __restrict__ h,
                               float* __restrict__ out_h, float* __restrict__ out_c)
{
    int idx = blockIdx.x * 256 + threadIdx.x;
    int r = idx >> 7, c = idx & 127;
    const float* g = gates + (size_t)r * G4;
    float gi = g[c]        + bih[c]        + bhh[c];
    float gf = g[128 + c]  + bih[128 + c]  + bhh[128 + c];
    float gg = g[256 + c]  + bih[256 + c]  + bhh[256 + c];
    float go = g[384 + c]  + bih[384 + c]  + bhh[384 + c];
    float cprev = lstm_c[idx] * masks[r];
    float cn = sigf(gf) * cprev + sigf(gi) * tanhf(gg);
    float hn = sigf(go) * tanhf(cn);
    h[idx] = hn;
    out_h[idx] = hn;
    out_c[idx] = cn;
}

// ---------------- persistent bidirectional GRU scan (MFMA, weights-stationary) --------
// 256 blocks (128 fwd + 128 bwd), 512 threads = 8 waves, 32 rows/block.
// Wave w owns h-columns [w*16,w*16+16). Whh stationary in regs (split-f16, 3-MFMA).
// U+bhh preloaded (24 regs); V rows {tt,tt+1} prefetched. W_hard logits = extra MFMA
// "gate" split across waves 0 (rows 0-15) and 1 (rows 16-31), 1-step delayed; results
// staged in LDS, one coalesced global write at the end (no in-loop global stores).
__global__ __launch_bounds__(512, 2)
void gru_scan(const float* __restrict__ WhhF, const float* __restrict__ WhhB,
              const float* __restrict__ bhhF, const float* __restrict__ bhhB,
              const float* __restrict__ Uf, const float* __restrict__ Vf,
              const float* __restrict__ Ub, const float* __restrict__ Vb,
              const float* __restrict__ Whard,
              float* __restrict__ partF, float* __restrict__ partB)
{
    __shared__ __align__(16) unsigned short hHi[2][32][LDSW];
    __shared__ __align__(16) unsigned short hLo[2][32][LDSW];
    __shared__ float partLds[32][64][2];

    const int t = threadIdx.x;
    const int dir = blockIdx.x >> 7;
    const int blk = blockIdx.x & 127;
    const int r0 = blk * 32;
    const int bbx = r0 >> 6;
    const int n0 = r0 & 63;
    const int w  = t >> 6;        // wave 0..7
    const int l  = t & 63;        // lane
    const int li = l & 15;
    const int lg = l >> 4;        // 0..3
    const int cl = w * 16 + li;   // owned h column 0..127

    const float* Whh = dir ? WhhB : WhhF;
    const float* bhh = dir ? bhhB : bhhF;
    const float* U   = dir ? Ub   : Uf;
    const float* V   = dir ? Vb   : Vf;
    float* part      = dir ? partB : partF;

    // stationary gate-weight fragments: B[k][n], n = cl, k = kt*32 + lg*8 + j
    f16x8 Bhi[3][4], Blo[3][4];
    #pragma unroll
    for (int g = 0; g < 3; ++g)
        #pragma unroll
        for (int kt = 0; kt < 4; ++kt) {
            const float* src = Whh + (size_t)(g * 128 + cl) * 128 + kt * 32 + lg * 8;
            #pragma unroll
            for (int j = 0; j < 8; ++j) {
                float wv = src[j];
                _Float16 hi = (_Float16)wv;
                _Float16 lo = (_Float16)((wv - (float)hi) * 1024.0f);
                Bhi[g][kt][j] = hi;
                Blo[g][kt][j] = lo;
            }
        }

    // W_hard pred fragments (waves 0,1): B[k][n=li<2]
    f16x8 Phi[4], Plo[4];
    if (w < 2) {
        #pragma unroll
        for (int kt = 0; kt < 4; ++kt) {
            #pragma unroll
            for (int j = 0; j < 8; ++j) {
                float wv = (li < 2) ? Whard[li * 256 + dir * 128 + kt * 32 + lg * 8 + j] : 0.0f;
                _Float16 hi = (_Float16)wv;
                _Float16 lo = (_Float16)((wv - (float)hi) * 1024.0f);
                Phi[kt][j] = hi;
                Plo[kt][j] = lo;
            }
        }
    }

    // step-invariant U gate values with bhh folded in
    const float bh_r = bhh[cl];
    const float bh_z = bhh[128 + cl];
    const float bh_n = bhh[256 + cl];
    float u_r[8], u_z[8], u_n[8];
    #pragma unroll
    for (int rt = 0; rt < 2; ++rt)
        #pragma unroll
        for (int rg = 0; rg < 4; ++rg) {
            const int idx = rt * 4 + rg;
            const int R = r0 + rt * 16 + lg * 4 + rg;
            const float* Ur = U + (size_t)R * G3;
            u_r[idx] = Ur[cl]       + bh_r;
            u_z[idx] = Ur[128 + cl] + bh_z;
            u_n[idx] = Ur[256 + cl] + bh_n;
        }

    // V pipeline: rows {tt, tt+1}, prefetched
    const int vbase = bbx << 6;
    float v0r, v0z, v0n, v1r, v1z, v1n;
    {
        const int tt0 = dir ? (NM - 1) : 0;
        const float* Vr0 = V + (size_t)(vbase + tt0) * G3;
        const float* Vr1 = V + (size_t)(vbase + tt0 + 1) * G3;
        v0r = Vr0[cl]; v0z = Vr0[128 + cl]; v0n = Vr0[256 + cl];
        v1r = Vr1[cl]; v1z = Vr1[128 + cl]; v1n = Vr1[256 + cl];
    }

    for (int i = t; i < 2 * 32 * LDSW; i += 512) {
        (&hHi[0][0][0])[i] = 0;
        (&hLo[0][0][0])[i] = 0;
    }
    float hreg[8] = {0.f,0.f,0.f,0.f,0.f,0.f,0.f,0.f};

    int cur = 0;
    __syncthreads();

    for (int s = 0; s < NM; ++s) {
        const int tt = dir ? (NM - 1 - s) : s;

        // next-step V prefetch (hides under MFMA)
        float p0r, p0z, p0n, p1r, p1z, p1n;
        {
            const int sn = (s + 1 < NM) ? s + 1 : s;
            const int ttn = dir ? (NM - 1 - sn) : sn;
            const float* Vr0 = V + (size_t)(vbase + ttn) * G3;
            const float* Vr1 = V + (size_t)(vbase + ttn + 1) * G3;
            p0r = Vr0[cl]; p0z = Vr0[128 + cl]; p0n = Vr0[256 + cl];
            p1r = Vr1[cl]; p1z = Vr1[128 + cl]; p1n = Vr1[256 + cl];
        }

        f32x4 accA[3][2], accB[3][2], pA, pB;
        #pragma unroll
        for (int g = 0; g < 3; ++g)
            #pragma unroll
            for (int rt = 0; rt < 2; ++rt) {
                accA[g][rt] = (f32x4){0.f,0.f,0.f,0.f};
                accB[g][rt] = (f32x4){0.f,0.f,0.f,0.f};
            }
        pA = pB = (f32x4){0.f,0.f,0.f,0.f};

        #pragma unroll
        for (int kt = 0; kt < 4; ++kt) {
            f16x8 Ahi[2], Alo[2];
            const int koff = kt * 32 + lg * 8;
            #pragma unroll
            for (int rt = 0; rt < 2; ++rt) {
                const int arow = rt * 16 + li;
                Ahi[rt] = *(const f16x8*)&hHi[cur][arow][koff];
                Alo[rt] = *(const f16x8*)&hLo[cur][arow][koff];
            }
            #pragma unroll
            for (int g = 0; g < 3; ++g)
                #pragma unroll
                for (int rt = 0; rt < 2; ++rt) {
                    accA[g][rt] = __builtin_amdgcn_mfma_f32_16x16x32_f16(Ahi[rt], Bhi[g][kt], accA[g][rt], 0, 0, 0);
                    accB[g][rt] = __builtin_amdgcn_mfma_f32_16x16x32_f16(Alo[rt], Bhi[g][kt], accB[g][rt], 0, 0, 0);
                    accB[g][rt] = __builtin_amdgcn_mfma_f32_16x16x32_f16(Ahi[rt], Blo[g][kt], accB[g][rt], 0, 0, 0);
                }
            if (w < 2) {   // pred "gate": wave w handles rt = w
                pA = __builtin_amdgcn_mfma_f32_16x16x32_f16(Ahi[w], Phi[kt], pA, 0, 0, 0);
                pB = __builtin_amdgcn_mfma_f32_16x16x32_f16(Alo[w], Phi[kt], pB, 0, 0, 0);
                pB = __builtin_amdgcn_mfma_f32_16x16x32_f16(Ahi[w], Plo[kt], pB, 0, 0, 0);
            }
        }

        // stage previous step's W_hard logits into LDS (computed from h_{s-1})
        if (w < 2 && s > 0 && li < 2) {
            const int ttp = dir ? (tt + 1) : (tt - 1);
            #pragma unroll
            for (int rg = 0; rg < 4; ++rg) {
                const int row = w * 16 + lg * 4 + rg;
                partLds[row][ttp][li] = pA[rg] + pB[rg] * 9.765625e-4f;
            }
        }

        // GRU pointwise epilogue
        #pragma unroll
        for (int rt = 0; rt < 2; ++rt) {
            #pragma unroll
            for (int rg = 0; rg < 4; ++rg) {
                const int idx = rt * 4 + rg;
                const int row = rt * 16 + lg * 4 + rg;
                const int n = n0 + row;
                const bool up = (tt >= n);
                const float vr_ = up ? v1r : v0r;
                const float vz_ = up ? v1z : v0z;
                const float vn_ = up ? v1n : v0n;
                const float gr = fmaf(accB[0][rt][rg], 9.765625e-4f, accA[0][rt][rg]);
                const float gz = fmaf(accB[1][rt][rg], 9.765625e-4f, accA[1][rt][rg]);
                const float gn = fmaf(accB[2][rt][rg], 9.765625e-4f, accA[2][rt][rg]);
                const float rr  = fsig(u_r[idx] + vr_ + gr);
                const float zz  = fsig(u_z[idx] + vz_ + gz);
                const float nn2 = ftanh(u_n[idx] + vn_ + rr * gn);
                hreg[idx] = fmaf(zz, hreg[idx] - nn2, nn2);
            }
        }

        v0r = p0r; v0z = p0z; v0n = p0n;
        v1r = p1r; v1z = p1z; v1n = p1n;

        // write split h to the other buffer (readers are on buf[cur]; no race)
        const int nxt = cur ^ 1;
        #pragma unroll
        for (int rt = 0; rt < 2; ++rt)
            #pragma unroll
            for (int rg = 0; rg < 4; ++rg) {
                const int row = rt * 16 + lg * 4 + rg;
                const float hn = hreg[rt * 4 + rg];
                _Float16 hi = (_Float16)hn;
                _Float16 lo = (_Float16)((hn - (float)hi) * 1024.0f);
                hHi[nxt][row][cl] = h2u(hi);
                hLo[nxt][row][cl] = h2u(lo);
            }
        cur = nxt;
        __syncthreads();
    }

    // final-step W_hard logits (h_{last} sits in buf[cur])
    if (w < 2) {
        f32x4 qA = (f32x4){0.f,0.f,0.f,0.f}, qB = (f32x4){0.f,0.f,0.f,0.f};
        #pragma unroll
        for (int kt = 0; kt < 4; ++kt) {
            const int koff = kt * 32 + lg * 8;
            f16x8 Ah = *(const f16x8*)&hHi[cur][w * 16 + li][koff];
            f16x8 Al = *(const f16x8*)&hLo[cur][w * 16 + li][koff];
            qA = __builtin_amdgcn_mfma_f32_16x16x32_f16(Ah, Phi[kt], qA, 0, 0, 0);
            qB = __builtin_amdgcn_mfma_f32_16x16x32_f16(Al, Phi[kt], qB, 0, 0, 0);
            qB = __builtin_amdgcn_mfma_f32_16x16x32_f16(Ah, Plo[kt], qB, 0, 0, 0);
        }
        if (li < 2) {
            const int ttl = dir ? 0 : NM - 1;
            #pragma unroll
            for (int rg = 0; rg < 4; ++rg) {
                const int row = w * 16 + lg * 4 + rg;
                partLds[row][ttl][li] = qA[rg] + qB[rg] * 9.765625e-4f;
            }
        }
    }
    __syncthreads();

    // coalesced bulk write of part logits: 32 rows x 126 floats
    {
        const int row = t >> 4;        // 16 threads per row
        const int seg = t & 15;        // 4 float2 each
        float* dst = part + (size_t)(r0 + row) * (NM * 2);
        #pragma unroll
        for (int k = 0; k < 4; ++k) {
            const int m = seg * 4 + k;
            if (m < NM) {
                float2 v = *(const float2*)&partLds[row][m][0];
                *(float2*)&dst[m * 2] = v;
            }
        }
    }
}

// ---------------- hard gate + soft attention + action head ----------------
__global__ __launch_bounds__(128)
void attn_final(const float* __restrict__ h, const float* __restrict__ q,
                const float* __restrict__ kk,
                const float* __restrict__ partF, const float* __restrict__ partB,
                const float* __restrict__ bhard, const float* __restrict__ gum,
                const float* __restrict__ Wact, const float* __restrict__ bact,
                float* __restrict__ out_act, float* __restrict__ out_alp)
{
    const int r = blockIdx.x;
    const int bbx = r >> 6, n = r & 63;
    const int t = threadIdx.x;
    __shared__ float qsh[HH], wsh[NM], shh[HH], shx[HH];
    if (t < HH) { qsh[t] = q[(size_t)r * HH + t]; shh[t] = h[(size_t)r * HH + t]; }
    __syncthreads();
    if (t < 64) {
        float sc = -INFINITY;
        float hardv = 0.0f;
        if (t < NM) {
            const int idxm = t + (t >= n ? 1 : 0);
            const float4* kr = (const float4*)(kk + (size_t)((bbx << 6) + idxm) * HH);
            float s = 0.0f;
            #pragma unroll
            for (int j4 = 0; j4 < 32; ++j4) {
                float4 kv = kr[j4];
                float4 qv = *(const float4*)&qsh[j4 * 4];
                s += kv.x * qv.x + kv.y * qv.y + kv.z * qv.z + kv.w * qv.w;
            }
            sc = s * 0.088388347648318447f;   // 1/sqrt(128)
            const float2 pf = *(const float2*)(partF + ((size_t)r * NM + t) * 2);
            const float2 pb = *(const float2*)(partB + ((size_t)r * NM + t) * 2);
            const float2 gv = *(const float2*)(gum + ((size_t)r * NM + t) * 2);
            const float l0 = pf.x + pb.x + bhard[0] + gv.x;
            const float l1 = pf.y + pb.y + bhard[1] + gv.y;
            hardv = (l1 > l0) ? 1.0f : 0.0f;
        }
        float mx = sc;
        #pragma unroll
        for (int d = 32; d; d >>= 1) mx = fmaxf(mx, __shfl_xor(mx, d, 64));
        const float e = (t < NM) ? expf(sc - mx) : 0.0f;
        float sum = e;
        #pragma unroll
        for (int d = 32; d; d >>= 1) sum += __shfl_xor(sum, d, 64);
        if (t < NM) wsh[t] = hardv * e / sum;
    }
    __syncthreads();
    {
        const int j = t;
        float x = 0.0f;
        for (int m = 0; m < NM; ++m) {
            const int idxm = m + (m >= n ? 1 : 0);
            x = fmaf(wsh[m], h[(size_t)((bbx << 6) + idxm) * HH + j], x);
        }
        shx[j] = x;
    }
    __syncthreads();
    if (t < 16) {
        const float* wa = Wact + (size_t)t * 256;
        float acc = bact[t];
        #pragma unroll
        for (int j4 = 0; j4 < 32; ++j4) {
            float4 w1 = *(const float4*)&wa[j4 * 4];
            float4 hv = *(const float4*)&shh[j4 * 4];
            float4 w2 = *(const float4*)&wa[128 + j4 * 4];
            float4 xv = *(const float4*)&shx[j4 * 4];
            acc += w1.x * hv.x + w1.y * hv.y + w1.z * hv.z + w1.w * hv.w
                 + w2.x * xv.x + w2.y * xv.y + w2.z * xv.z + w2.w * xv.w;
        }
        float mx = acc; int am = t;
        #pragma unroll
        for (int d = 8; d; d >>= 1) {
            const float om = __shfl_xor(mx, d, 16);
            const int   oa = __shfl_xor(am, d, 16);
            if (om > mx || (om == mx && oa < am)) { mx = om; am = oa; }
        }
        const float e = expf(acc - mx);
        float sum = e;
        #pragma unroll
        for (int d = 8; d; d >>= 1) sum += __shfl_xor(sum, d, 16);
        if (t == 0) {
            out_act[r] = (float)am;
            out_alp[r] = -logf(sum);
        }
    }
}

// ---------------- launch ----------------
extern "C" void kernel_launch(void* const* d_in, const int* in_sizes, int n_in,
                              void* d_out, int out_size, void* d_ws, size_t ws_size,
                              hipStream_t stream)
{
    const float* obs    = (const float*)d_in[0];
    const float* lstm_h = (const float*)d_in[1];
    const float* lstm_c = (const float*)d_in[2];
    const float* masks  = (const float*)d_in[3];
    const float* W_enc  = (const float*)d_in[4];
    const float* b_enc  = (const float*)d_in[5];
    const float* lWih   = (const float*)d_in[6];
    const float* lWhh   = (const float*)d_in[7];
    const float* lbih   = (const float*)d_in[8];
    const float* lbhh   = (const float*)d_in[9];
    const float* gWihf  = (const float*)d_in[10];
    const float* gWhhf  = (const float*)d_in[11];
    const float* gbihf  = (const float*)d_in[12];
    const float* gbihf2 = (const float*)d_in[13];
    const float* gWihb  = (const float*)d_in[14];
    const float* gWhhb  = (const float*)d_in[15];
    const float* gbihb  = (const float*)d_in[16];
    const float* gbihb2 = (const float*)d_in[17];
    const float* Whard  = (const float*)d_in[18];
    const float* bhard  = (const float*)d_in[19];
    const float* Wq     = (const float*)d_in[20];
    const float* Wk     = (const float*)d_in[21];
    const float* Wact   = (const float*)d_in[22];
    const float* bact   = (const float*)d_in[23];
    const float* gum    = (const float*)d_in[24];
    const float* gbhhf  = gbihf2;   // d_in[13] = gru_bhh_f
    const float* gbhhb  = gbihb2;   // d_in[17] = gru_bhh_b

    float* W = (float*)d_ws;
    float* h     = W; W += (size_t)BN_ * HH;
    float* henc  = W; W += (size_t)BN_ * HH;
    float* gates = W; W += (size_t)BN_ * G4;
    float* Uf    = W; W += (size_t)BN_ * G3;
    float* Vf    = W; W += (size_t)BN_ * G3;
    float* Ub    = W; W += (size_t)BN_ * G3;
    float* Vb    = W; W += (size_t)BN_ * G3;
    float* partF = W; W += (size_t)BN_ * NM * 2;
    float* partB = W; W += (size_t)BN_ * NM * 2;
    float* qq    = W; W += (size_t)BN_ * HH;
    float* kk    = W; W += (size_t)BN_ * HH;

    float* out_f   = (float*)d_out;
    float* out_act = out_f;                       // 4096
    float* out_alp = out_act + BN_;               // 4096
    float* out_h   = out_alp + BN_;               // 4096*128
    float* out_c   = out_h + (size_t)BN_ * HH;    // 4096*128

    gemm_tn<false, true, true, false><<<dim3(HH / 64, BN_ / 64), 256, 0, stream>>>(
        obs, OBS_, W_enc, OBS_, nullptr, 0, nullptr, 0, b_enc, nullptr, henc, HH, OBS_);
    gemm_tn<true, false, false, true><<<dim3(G4 / 64, BN_ / 64), 256, 0, stream>>>(
        henc, HH, lWih, HH, lstm_h, HH, lWhh, HH, nullptr, masks, gates, G4, HH);
    lstm_pointwise<<<BN_ * HH / 256, 256, 0, stream>>>(gates, lbih, lbhh, lstm_c, masks,
                                                       h, out_h, out_c);
    gemm_tn<false, false, true, false><<<dim3(G3 / 64, BN_ / 64), 256, 0, stream>>>(
        h, HH, gWihf, 2 * HH, nullptr, 0, nullptr, 0, gbihf, nullptr, Uf, G3, HH);
    gemm_tn<false, false, false, false><<<dim3(G3 / 64, BN_ / 64), 256, 0, stream>>>(
        h, HH, gWihf + HH, 2 * HH, nullptr, 0, nullptr, 0, nullptr, nullptr, Vf, G3, HH);
    gemm_tn<false, false, true, false><<<dim3(G3 / 64, BN_ / 64), 256, 0, stream>>>(
        h, HH, gWihb, 2 * HH, nullptr, 0, nullptr, 0, gbihb, nullptr, Ub, G3, HH);
    gemm_tn<false, false, false, false><<<dim3(G3 / 64, BN_ / 64), 256, 0, stream>>>(
        h, HH, gWihb + HH, 2 * HH, nullptr, 0, nullptr, 0, nullptr, nullptr, Vb, G3, HH);
    gemm_tn<false, false, false, false><<<dim3(HH / 64, BN_ / 64), 256, 0, stream>>>(
        h, HH, Wq, HH, nullptr, 0, nullptr, 0, nullptr, nullptr, qq, HH, HH);
    gemm_tn<false, false, false, false><<<dim3(HH / 64, BN_ / 64), 256, 0, stream>>>(
        h, HH, Wk, HH, nullptr, 0, nullptr, 0, nullptr, nullptr, kk, HH, HH);
    gru_scan<<<256, 512, 0, stream>>>(gWhhf, gWhhb, gbhhf, gbhhb, Uf, Vf, Ub, Vb,
                                      Whard, partF, partB);
    attn_final<<<BN_, 128, 0, stream>>>(h, qq, kk, partF, partB, bhard, gum,
                                        Wact, bact, out_act, out_alp);
}

// Round 10
// 295.786 us; speedup vs baseline: 2.4811x; 2.4811x over previous
//
#include <hip/hip_runtime.h>
#include <hip/hip_bf16.h>
#include <math.h>

#define BB   64
#define NN   64
#define HH   128
#define OBS_ 128
#define AA   16
#define BN_  4096
#define NM   63
#define G3   384
#define G4   512
#define LDSW 136   // ushorts/row

typedef _Float16 f16x8 __attribute__((ext_vector_type(8)));
typedef float    f32x4 __attribute__((ext_vector_type(4)));

__device__ __forceinline__ float sigf(float x) { return 1.0f / (1.0f + expf(-x)); }

// fast device transcendentals (v_exp_f32 / v_rcp_f32, ~2-3 ulp)
__device__ __forceinline__ float fsig(float x) {
    return __builtin_amdgcn_rcpf(1.0f + __builtin_amdgcn_exp2f(-1.4426950408889634f * x));
}
__device__ __forceinline__ float ftanh(float x) {
    return 1.0f - 2.0f * __builtin_amdgcn_rcpf(1.0f + __builtin_amdgcn_exp2f(2.8853900817779268f * x));
}

__device__ __forceinline__ unsigned short h2u(_Float16 h) {
    union { _Float16 f; unsigned short u; } cv; cv.f = h; return cv.u;
}

// ---- generic C = A@B^T (+ A2@B2^T) (+bias)(+relu)(+row-mask on A2), tile 64x64 ----
template<bool DUAL, bool RELU, bool BIAS, bool RMASK>
__global__ __launch_bounds__(256)
void gemm_tn(const float* __restrict__ A, int lda,
             const float* __restrict__ B, int ldb,
             const float* __restrict__ A2, int lda2,
             const float* __restrict__ B2, int ldb2,
             const float* __restrict__ bias,
             const float* __restrict__ rmask,
             float* __restrict__ C, int ldc, int K)
{
    __shared__ float As[32][68];
    __shared__ float Bs[32][68];
    const int t = threadIdx.x;
    const int tx = t & 15, ty = t >> 4;
    const int row0 = blockIdx.y * 64, col0 = blockIdx.x * 64;
    const int lm = t >> 2;           // 0..63
    const int lk = (t & 3) * 8;      // 0,8,16,24
    float acc[4][4] = {};
    const int npass = DUAL ? 2 : 1;
    for (int pass = 0; pass < npass; ++pass) {
        const float* Ap = pass ? A2 : A; const int ldap = pass ? lda2 : lda;
        const float* Bp = pass ? B2 : B; const int ldbp = pass ? ldb2 : ldb;
        for (int k0 = 0; k0 < K; k0 += 32) {
            __syncthreads();
            {
                const float* srcA = Ap + (size_t)(row0 + lm) * ldap + k0 + lk;
                float4 a0 = *(const float4*)(srcA);
                float4 a1 = *(const float4*)(srcA + 4);
                if (RMASK && pass == 1) {
                    const float mk = rmask[row0 + lm];
                    a0.x *= mk; a0.y *= mk; a0.z *= mk; a0.w *= mk;
                    a1.x *= mk; a1.y *= mk; a1.z *= mk; a1.w *= mk;
                }
                As[lk + 0][lm] = a0.x; As[lk + 1][lm] = a0.y; As[lk + 2][lm] = a0.z; As[lk + 3][lm] = a0.w;
                As[lk + 4][lm] = a1.x; As[lk + 5][lm] = a1.y; As[lk + 6][lm] = a1.z; As[lk + 7][lm] = a1.w;
                const float* srcB = Bp + (size_t)(col0 + lm) * ldbp + k0 + lk;
                float4 b0 = *(const float4*)(srcB);
                float4 b1 = *(const float4*)(srcB + 4);
                Bs[lk + 0][lm] = b0.x; Bs[lk + 1][lm] = b0.y; Bs[lk + 2][lm] = b0.z; Bs[lk + 3][lm] = b0.w;
                Bs[lk + 4][lm] = b1.x; Bs[lk + 5][lm] = b1.y; Bs[lk + 6][lm] = b1.z; Bs[lk + 7][lm] = b1.w;
            }
            __syncthreads();
            #pragma unroll
            for (int k = 0; k < 32; ++k) {
                float av[4], bv[4];
                *(float4*)av = *(const float4*)&As[k][ty * 4];
                *(float4*)bv = *(const float4*)&Bs[k][tx * 4];
                #pragma unroll
                for (int i = 0; i < 4; ++i)
                    #pragma unroll
                    for (int j = 0; j < 4; ++j)
                        acc[i][j] = fmaf(av[i], bv[j], acc[i][j]);
            }
        }
    }
    #pragma unroll
    for (int i = 0; i < 4; ++i) {
        const int r = row0 + ty * 4 + i;
        const int c = col0 + tx * 4;
        float vv[4];
        #pragma unroll
        for (int j = 0; j < 4; ++j) {
            float x = acc[i][j];
            if (BIAS) x += bias[c + j];
            if (RELU) x = fmaxf(x, 0.0f);
            vv[j] = x;
        }
        *(float4*)&C[(size_t)r * ldc + c] = *(float4*)vv;
    }
}

__global__ void lstm_pointwise(const float* __restrict__ gates,
                               const float* __restrict__ bih, const float* __restrict__ bhh,
                               const float* __restrict__ lstm_c, const float* __restrict__ masks,
                               float* __restrict__ h,
                               float* __restrict__ out_h, float* __restrict__ out_c)
{
    int idx = blockIdx.x * 256 + threadIdx.x;
    int r = idx >> 7, c = idx & 127;
    const float* g = gates + (size_t)r * G4;
    float gi = g[c]        + bih[c]        + bhh[c];
    float gf = g[128 + c]  + bih[128 + c]  + bhh[128 + c];
    float gg = g[256 + c]  + bih[256 + c]  + bhh[256 + c];
    float go = g[384 + c]  + bih[384 + c]  + bhh[384 + c];
    float cprev = lstm_c[idx] * masks[r];
    float cn = sigf(gf) * cprev + sigf(gi) * tanhf(gg);
    float hn = sigf(go) * tanhf(cn);
    h[idx] = hn;
    out_h[idx] = hn;
    out_c[idx] = cn;
}

// ---------------- persistent bidirectional GRU scan (MFMA, weights-stationary) --------
// 256 blocks (128 fwd + 128 bwd), 512 threads = 8 waves, 32 rows/block.
// Wave w owns h-columns [w*16,w*16+16). Whh stationary in regs (split-f16, 3-MFMA).
// U+bhh preloaded (24 regs); V rows {tt,tt+1} prefetched. W_hard logits = extra MFMA
// "gate" on waves 0/1 (rt picked by STATIC select, not runtime index -> no scratch),
// 1-step delayed; staged in LDS, one coalesced global write at the end.
__global__ __launch_bounds__(512, 2)
void gru_scan(const float* __restrict__ WhhF, const float* __restrict__ WhhB,
              const float* __restrict__ bhhF, const float* __restrict__ bhhB,
              const float* __restrict__ Uf, const float* __restrict__ Vf,
              const float* __restrict__ Ub, const float* __restrict__ Vb,
              const float* __restrict__ Whard,
              float* __restrict__ partF, float* __restrict__ partB)
{
    __shared__ __align__(16) unsigned short hHi[2][32][LDSW];
    __shared__ __align__(16) unsigned short hLo[2][32][LDSW];
    __shared__ float partLds[32][64][2];

    const int t = threadIdx.x;
    const int dir = blockIdx.x >> 7;
    const int blk = blockIdx.x & 127;
    const int r0 = blk * 32;
    const int bbx = r0 >> 6;
    const int n0 = r0 & 63;
    const int w  = t >> 6;        // wave 0..7
    const int l  = t & 63;        // lane
    const int li = l & 15;
    const int lg = l >> 4;        // 0..3
    const int cl = w * 16 + li;   // owned h column 0..127
    const bool pw = (w < 2);      // pred waves

    const float* Whh = dir ? WhhB : WhhF;
    const float* bhh = dir ? bhhB : bhhF;
    const float* U   = dir ? Ub   : Uf;
    const float* V   = dir ? Vb   : Vf;
    float* part      = dir ? partB : partF;

    // stationary gate-weight fragments: B[k][n], n = cl, k = kt*32 + lg*8 + j
    f16x8 Bhi[3][4], Blo[3][4];
    #pragma unroll
    for (int g = 0; g < 3; ++g)
        #pragma unroll
        for (int kt = 0; kt < 4; ++kt) {
            const float* src = Whh + (size_t)(g * 128 + cl) * 128 + kt * 32 + lg * 8;
            #pragma unroll
            for (int j = 0; j < 8; ++j) {
                float wv = src[j];
                _Float16 hi = (_Float16)wv;
                _Float16 lo = (_Float16)((wv - (float)hi) * 1024.0f);
                Bhi[g][kt][j] = hi;
                Blo[g][kt][j] = lo;
            }
        }

    // W_hard pred fragments (waves 0,1): B[k][n=li<2]
    f16x8 Phi[4], Plo[4];
    if (pw) {
        #pragma unroll
        for (int kt = 0; kt < 4; ++kt) {
            #pragma unroll
            for (int j = 0; j < 8; ++j) {
                float wv = (li < 2) ? Whard[li * 256 + dir * 128 + kt * 32 + lg * 8 + j] : 0.0f;
                _Float16 hi = (_Float16)wv;
                _Float16 lo = (_Float16)((wv - (float)hi) * 1024.0f);
                Phi[kt][j] = hi;
                Plo[kt][j] = lo;
            }
        }
    }

    // step-invariant U gate values with bhh folded in
    const float bh_r = bhh[cl];
    const float bh_z = bhh[128 + cl];
    const float bh_n = bhh[256 + cl];
    float u_r[8], u_z[8], u_n[8];
    #pragma unroll
    for (int rt = 0; rt < 2; ++rt)
        #pragma unroll
        for (int rg = 0; rg < 4; ++rg) {
            const int idx = rt * 4 + rg;
            const int R = r0 + rt * 16 + lg * 4 + rg;
            const float* Ur = U + (size_t)R * G3;
            u_r[idx] = Ur[cl]       + bh_r;
            u_z[idx] = Ur[128 + cl] + bh_z;
            u_n[idx] = Ur[256 + cl] + bh_n;
        }

    // V pipeline: rows {tt, tt+1}, prefetched
    const int vbase = bbx << 6;
    float v0r, v0z, v0n, v1r, v1z, v1n;
    {
        const int tt0 = dir ? (NM - 1) : 0;
        const float* Vr0 = V + (size_t)(vbase + tt0) * G3;
        const float* Vr1 = V + (size_t)(vbase + tt0 + 1) * G3;
        v0r = Vr0[cl]; v0z = Vr0[128 + cl]; v0n = Vr0[256 + cl];
        v1r = Vr1[cl]; v1z = Vr1[128 + cl]; v1n = Vr1[256 + cl];
    }

    for (int i = t; i < 2 * 32 * LDSW; i += 512) {
        (&hHi[0][0][0])[i] = 0;
        (&hLo[0][0][0])[i] = 0;
    }
    float hreg[8] = {0.f,0.f,0.f,0.f,0.f,0.f,0.f,0.f};

    int cur = 0;
    __syncthreads();

    for (int s = 0; s < NM; ++s) {
        const int tt = dir ? (NM - 1 - s) : s;

        // next-step V prefetch (hides under MFMA)
        float p0r, p0z, p0n, p1r, p1z, p1n;
        {
            const int sn = (s + 1 < NM) ? s + 1 : s;
            const int ttn = dir ? (NM - 1 - sn) : sn;
            const float* Vr0 = V + (size_t)(vbase + ttn) * G3;
            const float* Vr1 = V + (size_t)(vbase + ttn + 1) * G3;
            p0r = Vr0[cl]; p0z = Vr0[128 + cl]; p0n = Vr0[256 + cl];
            p1r = Vr1[cl]; p1z = Vr1[128 + cl]; p1n = Vr1[256 + cl];
        }

        f32x4 accA[3][2], accB[3][2], pA, pB;
        #pragma unroll
        for (int g = 0; g < 3; ++g)
            #pragma unroll
            for (int rt = 0; rt < 2; ++rt) {
                accA[g][rt] = (f32x4){0.f,0.f,0.f,0.f};
                accB[g][rt] = (f32x4){0.f,0.f,0.f,0.f};
            }
        pA = pB = (f32x4){0.f,0.f,0.f,0.f};

        #pragma unroll
        for (int kt = 0; kt < 4; ++kt) {
            f16x8 Ahi[2], Alo[2];
            const int koff = kt * 32 + lg * 8;
            #pragma unroll
            for (int rt = 0; rt < 2; ++rt) {
                const int arow = rt * 16 + li;
                Ahi[rt] = *(const f16x8*)&hHi[cur][arow][koff];
                Alo[rt] = *(const f16x8*)&hLo[cur][arow][koff];
            }
            #pragma unroll
            for (int g = 0; g < 3; ++g)
                #pragma unroll
                for (int rt = 0; rt < 2; ++rt) {
                    accA[g][rt] = __builtin_amdgcn_mfma_f32_16x16x32_f16(Ahi[rt], Bhi[g][kt], accA[g][rt], 0, 0, 0);
                    accB[g][rt] = __builtin_amdgcn_mfma_f32_16x16x32_f16(Alo[rt], Bhi[g][kt], accB[g][rt], 0, 0, 0);
                    accB[g][rt] = __builtin_amdgcn_mfma_f32_16x16x32_f16(Ahi[rt], Blo[g][kt], accB[g][rt], 0, 0, 0);
                }
            if (pw) {   // pred "gate": wave w handles rt = w -- STATIC select, no runtime array index
                const f16x8 Aph = (w == 0) ? Ahi[0] : Ahi[1];
                const f16x8 Apl = (w == 0) ? Alo[0] : Alo[1];
                pA = __builtin_amdgcn_mfma_f32_16x16x32_f16(Aph, Phi[kt], pA, 0, 0, 0);
                pB = __builtin_amdgcn_mfma_f32_16x16x32_f16(Apl, Phi[kt], pB, 0, 0, 0);
                pB = __builtin_amdgcn_mfma_f32_16x16x32_f16(Aph, Plo[kt], pB, 0, 0, 0);
            }
        }

        // stage previous step's W_hard logits into LDS (computed from h_{s-1})
        if (pw && s > 0 && li < 2) {
            const int ttp = dir ? (tt + 1) : (tt - 1);
            #pragma unroll
            for (int rg = 0; rg < 4; ++rg) {
                const int row = w * 16 + lg * 4 + rg;
                partLds[row][ttp][li] = pA[rg] + pB[rg] * 9.765625e-4f;
            }
        }

        // GRU pointwise epilogue
        #pragma unroll
        for (int rt = 0; rt < 2; ++rt) {
            #pragma unroll
            for (int rg = 0; rg < 4; ++rg) {
                const int idx = rt * 4 + rg;
                const int row = rt * 16 + lg * 4 + rg;
                const int n = n0 + row;
                const bool up = (tt >= n);
                const float vr_ = up ? v1r : v0r;
                const float vz_ = up ? v1z : v0z;
                const float vn_ = up ? v1n : v0n;
                const float gr = fmaf(accB[0][rt][rg], 9.765625e-4f, accA[0][rt][rg]);
                const float gz = fmaf(accB[1][rt][rg], 9.765625e-4f, accA[1][rt][rg]);
                const float gn = fmaf(accB[2][rt][rg], 9.765625e-4f, accA[2][rt][rg]);
                const float rr  = fsig(u_r[idx] + vr_ + gr);
                const float zz  = fsig(u_z[idx] + vz_ + gz);
                const float nn2 = ftanh(u_n[idx] + vn_ + rr * gn);
                hreg[idx] = fmaf(zz, hreg[idx] - nn2, nn2);
            }
        }

        v0r = p0r; v0z = p0z; v0n = p0n;
        v1r = p1r; v1z = p1z; v1n = p1n;

        // write split h to the other buffer (readers are on buf[cur]; no race)
        const int nxt = cur ^ 1;
        #pragma unroll
        for (int rt = 0; rt < 2; ++rt)
            #pragma unroll
            for (int rg = 0; rg < 4; ++rg) {
                const int row = rt * 16 + lg * 4 + rg;
                const float hn = hreg[rt * 4 + rg];
                _Float16 hi = (_Float16)hn;
                _Float16 lo = (_Float16)((hn - (float)hi) * 1024.0f);
                hHi[nxt][row][cl] = h2u(hi);
                hLo[nxt][row][cl] = h2u(lo);
            }
        cur = nxt;
        __syncthreads();
    }

    // final-step W_hard logits (h_{last} sits in buf[cur])
    if (pw) {
        f32x4 qA = (f32x4){0.f,0.f,0.f,0.f}, qB = (f32x4){0.f,0.f,0.f,0.f};
        #pragma unroll
        for (int kt = 0; kt < 4; ++kt) {
            const int koff = kt * 32 + lg * 8;
            f16x8 Ah = *(const f16x8*)&hHi[cur][w * 16 + li][koff];
            f16x8 Al = *(const f16x8*)&hLo[cur][w * 16 + li][koff];
            qA = __builtin_amdgcn_mfma_f32_16x16x32_f16(Ah, Phi[kt], qA, 0, 0, 0);
            qB = __builtin_amdgcn_mfma_f32_16x16x32_f16(Al, Phi[kt], qB, 0, 0, 0);
            qB = __builtin_amdgcn_mfma_f32_16x16x32_f16(Ah, Plo[kt], qB, 0, 0, 0);
        }
        if (li < 2) {
            const int ttl = dir ? 0 : NM - 1;
            #pragma unroll
            for (int rg = 0; rg < 4; ++rg) {
                const int row = w * 16 + lg * 4 + rg;
                partLds[row][ttl][li] = qA[rg] + qB[rg] * 9.765625e-4f;
            }
        }
    }
    __syncthreads();

    // coalesced bulk write of part logits: 32 rows x 126 floats
    {
        const int row = t >> 4;        // 16 threads per row
        const int seg = t & 15;        // 4 float2 each
        float* dst = part + (size_t)(r0 + row) * (NM * 2);
        #pragma unroll
        for (int k = 0; k < 4; ++k) {
            const int m = seg * 4 + k;
            if (m < NM) {
                float2 v = *(const float2*)&partLds[row][m][0];
                *(float2*)&dst[m * 2] = v;
            }
        }
    }
}

// ---------------- hard gate + soft attention + action head ----------------
__global__ __launch_bounds__(128)
void attn_final(const float* __restrict__ h, const float* __restrict__ q,
                const float* __restrict__ kk,
                const float* __restrict__ partF, const float* __restrict__ partB,
                const float* __restrict__ bhard, const float* __restrict__ gum,
                const float* __restrict__ Wact, const float* __restrict__ bact,
                float* __restrict__ out_act, float* __restrict__ out_alp)
{
    const int r = blockIdx.x;
    const int bbx = r >> 6, n = r & 63;
    const int t = threadIdx.x;
    __shared__ float qsh[HH], wsh[NM], shh[HH], shx[HH];
    if (t < HH) { qsh[t] = q[(size_t)r * HH + t]; shh[t] = h[(size_t)r * HH + t]; }
    __syncthreads();
    if (t < 64) {
        float sc = -INFINITY;
        float hardv = 0.0f;
        if (t < NM) {
            const int idxm = t + (t >= n ? 1 : 0);
            const float4* kr = (const float4*)(kk + (size_t)((bbx << 6) + idxm) * HH);
            float s = 0.0f;
            #pragma unroll
            for (int j4 = 0; j4 < 32; ++j4) {
                float4 kv = kr[j4];
                float4 qv = *(const float4*)&qsh[j4 * 4];
                s += kv.x * qv.x + kv.y * qv.y + kv.z * qv.z + kv.w * qv.w;
            }
            sc = s * 0.088388347648318447f;   // 1/sqrt(128)
            const float2 pf = *(const float2*)(partF + ((size_t)r * NM + t) * 2);
            const float2 pb = *(const float2*)(partB + ((size_t)r * NM + t) * 2);
            const float2 gv = *(const float2*)(gum + ((size_t)r * NM + t) * 2);
            const float l0 = pf.x + pb.x + bhard[0] + gv.x;
            const float l1 = pf.y + pb.y + bhard[1] + gv.y;
            hardv = (l1 > l0) ? 1.0f : 0.0f;
        }
        float mx = sc;
        #pragma unroll
        for (int d = 32; d; d >>= 1) mx = fmaxf(mx, __shfl_xor(mx, d, 64));
        const float e = (t < NM) ? expf(sc - mx) : 0.0f;
        float sum = e;
        #pragma unroll
        for (int d = 32; d; d >>= 1) sum += __shfl_xor(sum, d, 64);
        if (t < NM) wsh[t] = hardv * e / sum;
    }
    __syncthreads();
    {
        const int j = t;
        float x = 0.0f;
        for (int m = 0; m < NM; ++m) {
            const int idxm = m + (m >= n ? 1 : 0);
            x = fmaf(wsh[m], h[(size_t)((bbx << 6) + idxm) * HH + j], x);
        }
        shx[j] = x;
    }
    __syncthreads();
    if (t < 16) {
        const float* wa = Wact + (size_t)t * 256;
        float acc = bact[t];
        #pragma unroll
        for (int j4 = 0; j4 < 32; ++j4) {
            float4 w1 = *(const float4*)&wa[j4 * 4];
            float4 hv = *(const float4*)&shh[j4 * 4];
            float4 w2 = *(const float4*)&wa[128 + j4 * 4];
            float4 xv = *(const float4*)&shx[j4 * 4];
            acc += w1.x * hv.x + w1.y * hv.y + w1.z * hv.z + w1.w * hv.w
                 + w2.x * xv.x + w2.y * xv.y + w2.z * xv.z + w2.w * xv.w;
        }
        float mx = acc; int am = t;
        #pragma unroll
        for (int d = 8; d; d >>= 1) {
            const float om = __shfl_xor(mx, d, 16);
            const int   oa = __shfl_xor(am, d, 16);
            if (om > mx || (om == mx && oa < am)) { mx = om; am = oa; }
        }
        const float e = expf(acc - mx);
        float sum = e;
        #pragma unroll
        for (int d = 8; d; d >>= 1) sum += __shfl_xor(sum, d, 16);
        if (t == 0) {
            out_act[r] = (float)am;
            out_alp[r] = -logf(sum);
        }
    }
}

// ---------------- launch ----------------
extern "C" void kernel_launch(void* const* d_in, const int* in_sizes, int n_in,
                              void* d_out, int out_size, void* d_ws, size_t ws_size,
                              hipStream_t stream)
{
    const float* obs    = (const float*)d_in[0];
    const float* lstm_h = (const float*)d_in[1];
    const float* lstm_c = (const float*)d_in[2];
    const float* masks  = (const float*)d_in[3];
    const float* W_enc  = (const float*)d_in[4];
    const float* b_enc  = (const float*)d_in[5];
    const float* lWih   = (const float*)d_in[6];
    const float* lWhh   = (const float*)d_in[7];
    const float* lbih   = (const float*)d_in[8];
    const float* lbhh   = (const float*)d_in[9];
    const float* gWihf  = (const float*)d_in[10];
    const float* gWhhf  = (const float*)d_in[11];
    const float* gbihf  = (const float*)d_in[12];
    const float* gbhhf  = (const float*)d_in[13];
    const float* gWihb  = (const float*)d_in[14];
    const float* gWhhb  = (const float*)d_in[15];
    const float* gbihb  = (const float*)d_in[16];
    const float* gbhhb  = (const float*)d_in[17];
    const float* Whard  = (const float*)d_in[18];
    const float* bhard  = (const float*)d_in[19];
    const float* Wq     = (const float*)d_in[20];
    const float* Wk     = (const float*)d_in[21];
    const float* Wact   = (const float*)d_in[22];
    const float* bact   = (const float*)d_in[23];
    const float* gum    = (const float*)d_in[24];

    float* W = (float*)d_ws;
    float* h     = W; W += (size_t)BN_ * HH;
    float* henc  = W; W += (size_t)BN_ * HH;
    float* gates = W; W += (size_t)BN_ * G4;
    float* Uf    = W; W += (size_t)BN_ * G3;
    float* Vf    = W; W += (size_t)BN_ * G3;
    float* Ub    = W; W += (size_t)BN_ * G3;
    float* Vb    = W; W += (size_t)BN_ * G3;
    float* partF = W; W += (size_t)BN_ * NM * 2;
    float* partB = W; W += (size_t)BN_ * NM * 2;
    float* qq    = W; W += (size_t)BN_ * HH;
    float* kk    = W; W += (size_t)BN_ * HH;

    float* out_f   = (float*)d_out;
    float* out_act = out_f;                       // 4096
    float* out_alp = out_act + BN_;               // 4096
    float* out_h   = out_alp + BN_;               // 4096*128
    float* out_c   = out_h + (size_t)BN_ * HH;    // 4096*128

    gemm_tn<false, true, true, false><<<dim3(HH / 64, BN_ / 64), 256, 0, stream>>>(
        obs, OBS_, W_enc, OBS_, nullptr, 0, nullptr, 0, b_enc, nullptr, henc, HH, OBS_);
    gemm_tn<true, false, false, true><<<dim3(G4 / 64, BN_ / 64), 256, 0, stream>>>(
        henc, HH, lWih, HH, lstm_h, HH, lWhh, HH, nullptr, masks, gates, G4, HH);
    lstm_pointwise<<<BN_ * HH / 256, 256, 0, stream>>>(gates, lbih, lbhh, lstm_c, masks,
                                                       h, out_h, out_c);
    gemm_tn<false, false, true, false><<<dim3(G3 / 64, BN_ / 64), 256, 0, stream>>>(
        h, HH, gWihf, 2 * HH, nullptr, 0, nullptr, 0, gbihf, nullptr, Uf, G3, HH);
    gemm_tn<false, false, false, false><<<dim3(G3 / 64, BN_ / 64), 256, 0, stream>>>(
        h, HH, gWihf + HH, 2 * HH, nullptr, 0, nullptr, 0, nullptr, nullptr, Vf, G3, HH);
    gemm_tn<false, false, true, false><<<dim3(G3 / 64, BN_ / 64), 256, 0, stream>>>(
        h, HH, gWihb, 2 * HH, nullptr, 0, nullptr, 0, gbihb, nullptr, Ub, G3, HH);
    gemm_tn<false, false, false, false><<<dim3(G3 / 64, BN_ / 64), 256, 0, stream>>>(
        h, HH, gWihb + HH, 2 * HH, nullptr, 0, nullptr, 0, nullptr, nullptr, Vb, G3, HH);
    gemm_tn<false, false, false, false><<<dim3(HH / 64, BN_ / 64), 256, 0, stream>>>(
        h, HH, Wq, HH, nullptr, 0, nullptr, 0, nullptr, nullptr, qq, HH, HH);
    gemm_tn<false, false, false, false><<<dim3(HH / 64, BN_ / 64), 256, 0, stream>>>(
        h, HH, Wk, HH, nullptr, 0, nullptr, 0, nullptr, nullptr, kk, HH, HH);
    gru_scan<<<256, 512, 0, stream>>>(gWhhf, gWhhb, gbhhf, gbhhb, Uf, Vf, Ub, Vb,
                                      Whard, partF, partB);
    attn_final<<<BN_, 128, 0, stream>>>(h, qq, kk, partF, partB, bhard, gum,
                                        Wact, bact, out_act, out_alp);
}

// Round 11
// 253.859 us; speedup vs baseline: 2.8909x; 1.1652x over previous
//
#include <hip/hip_runtime.h>
#include <hip/hip_bf16.h>
#include <math.h>

#define BB   64
#define NN   64
#define HH   128
#define OBS_ 128
#define AA   16
#define BN_  4096
#define NM   63
#define G3   384
#define G4   512
#define UVS  1536      // combined U|V row stride
#define QKS  256       // combined Q|K row stride
#define LDSW 136       // ushorts/row

typedef _Float16 f16x8 __attribute__((ext_vector_type(8)));
typedef float    f32x4 __attribute__((ext_vector_type(4)));

// fast device transcendentals (v_exp_f32 / v_rcp_f32, ~2-3 ulp)
__device__ __forceinline__ float fsig(float x) {
    return __builtin_amdgcn_rcpf(1.0f + __builtin_amdgcn_exp2f(-1.4426950408889634f * x));
}
__device__ __forceinline__ float ftanh(float x) {
    return 1.0f - 2.0f * __builtin_amdgcn_rcpf(1.0f + __builtin_amdgcn_exp2f(2.8853900817779268f * x));
}

__device__ __forceinline__ unsigned short h2u(_Float16 h) {
    union { _Float16 f; unsigned short u; } cv; cv.f = h; return cv.u;
}

// ---------------- MFMA GEMM: C = A@B^T (+ A2@B2^T) with split-f16 precision ----------
// 64x64 tile, 256 threads = 4 waves; wave w owns cols [w*16, w*16+16).
// N is segmented: seg = bx / tilesPerSeg picks B base + bias (for fused U|V / Q|K).
template<bool DUAL, bool RELU, bool RMASK>
__global__ __launch_bounds__(256)
void gemm_mfma(const float* __restrict__ A, int lda,
               const float* __restrict__ A2, int lda2,
               const float* __restrict__ rmask,
               const float* __restrict__ Bs0, const float* __restrict__ Bs1,
               const float* __restrict__ Bs2, const float* __restrict__ Bs3,
               const float* __restrict__ Bd, int ldb, int tilesPerSeg,
               const float* __restrict__ bias0, const float* __restrict__ bias1,
               const float* __restrict__ bias2, const float* __restrict__ bias3,
               float* __restrict__ C, int ldc)
{
    __shared__ __align__(16) unsigned short aHi[64][LDSW];
    __shared__ __align__(16) unsigned short aLo[64][LDSW];

    const int t = threadIdx.x;
    const int w = t >> 6, l = t & 63, li = l & 15, lg = l >> 4;
    const int bx = blockIdx.x, by = blockIdx.y;
    const int seg = bx / tilesPerSeg;
    const int cts = (bx % tilesPerSeg) * 64;
    const float* Bseg    = seg == 0 ? Bs0  : seg == 1 ? Bs1  : seg == 2 ? Bs2  : Bs3;
    const float* biasSeg = seg == 0 ? bias0 : seg == 1 ? bias1 : seg == 2 ? bias2 : bias3;
    const int row0 = by * 64;
    const int cl = w * 16 + li;

    f32x4 accA[4], accB[4];
    #pragma unroll
    for (int rt = 0; rt < 4; ++rt) {
        accA[rt] = (f32x4){0.f,0.f,0.f,0.f};
        accB[rt] = (f32x4){0.f,0.f,0.f,0.f};
    }

    const int npass = DUAL ? 2 : 1;
    for (int pass = 0; pass < npass; ++pass) {
        const float* Ap = pass ? A2 : A;
        const int ldap = pass ? lda2 : lda;
        __syncthreads();                     // guard LDS reuse across passes
        {   // stage A tile 64x128 as split-f16: thread -> row t>>2, 32 k-values
            const int ar = t >> 2, kof = (t & 3) * 32;
            const float* src = Ap + (size_t)(row0 + ar) * ldap + kof;
            float mk = 1.0f;
            if (RMASK && pass == 1) mk = rmask[row0 + ar];
            #pragma unroll
            for (int q = 0; q < 8; ++q) {
                float4 v = *(const float4*)(src + q * 4);
                if (RMASK && pass == 1) { v.x *= mk; v.y *= mk; v.z *= mk; v.w *= mk; }
                float vv[4] = {v.x, v.y, v.z, v.w};
                unsigned int hi01, hi23, lo01, lo23;
                {
                    _Float16 h0 = (_Float16)vv[0], h1 = (_Float16)vv[1];
                    _Float16 h2 = (_Float16)vv[2], h3 = (_Float16)vv[3];
                    _Float16 l0 = (_Float16)((vv[0] - (float)h0) * 1024.0f);
                    _Float16 l1 = (_Float16)((vv[1] - (float)h1) * 1024.0f);
                    _Float16 l2 = (_Float16)((vv[2] - (float)h2) * 1024.0f);
                    _Float16 l3 = (_Float16)((vv[3] - (float)h3) * 1024.0f);
                    hi01 = (unsigned int)h2u(h0) | ((unsigned int)h2u(h1) << 16);
                    hi23 = (unsigned int)h2u(h2) | ((unsigned int)h2u(h3) << 16);
                    lo01 = (unsigned int)h2u(l0) | ((unsigned int)h2u(l1) << 16);
                    lo23 = (unsigned int)h2u(l2) | ((unsigned int)h2u(l3) << 16);
                }
                *(uint2*)&aHi[ar][kof + q * 4] = make_uint2(hi01, hi23);
                *(uint2*)&aLo[ar][kof + q * 4] = make_uint2(lo01, lo23);
            }
        }
        // B fragments for this pass: col cts+cl, k = kt*32 + lg*8 + j
        const float* Bp = (DUAL && pass) ? Bd : Bseg;
        f16x8 bhi[4], blo[4];
        #pragma unroll
        for (int kt = 0; kt < 4; ++kt) {
            const float* srcB = Bp + (size_t)(cts + cl) * ldb + kt * 32 + lg * 8;
            #pragma unroll
            for (int j = 0; j < 8; ++j) {
                float wv = srcB[j];
                _Float16 hi = (_Float16)wv;
                _Float16 lo = (_Float16)((wv - (float)hi) * 1024.0f);
                bhi[kt][j] = hi;
                blo[kt][j] = lo;
            }
        }
        __syncthreads();
        #pragma unroll
        for (int kt = 0; kt < 4; ++kt) {
            const int koff = kt * 32 + lg * 8;
            #pragma unroll
            for (int rt = 0; rt < 4; ++rt) {
                f16x8 ah = *(const f16x8*)&aHi[rt * 16 + li][koff];
                f16x8 al = *(const f16x8*)&aLo[rt * 16 + li][koff];
                accA[rt] = __builtin_amdgcn_mfma_f32_16x16x32_f16(ah, bhi[kt], accA[rt], 0, 0, 0);
                accB[rt] = __builtin_amdgcn_mfma_f32_16x16x32_f16(al, bhi[kt], accB[rt], 0, 0, 0);
                accB[rt] = __builtin_amdgcn_mfma_f32_16x16x32_f16(ah, blo[kt], accB[rt], 0, 0, 0);
            }
        }
    }

    const float bv = biasSeg ? biasSeg[cts + cl] : 0.0f;
    const int gcol = bx * 64 + cl;
    #pragma unroll
    for (int rt = 0; rt < 4; ++rt)
        #pragma unroll
        for (int rg = 0; rg < 4; ++rg) {
            float x = fmaf(accB[rt][rg], 9.765625e-4f, accA[rt][rg]) + bv;
            if (RELU) x = fmaxf(x, 0.0f);
            const int r = row0 + rt * 16 + lg * 4 + rg;
            C[(size_t)r * ldc + gcol] = x;
        }
}

__global__ void lstm_pointwise(const float* __restrict__ gates,
                               const float* __restrict__ bih, const float* __restrict__ bhh,
                               const float* __restrict__ lstm_c, const float* __restrict__ masks,
                               float* __restrict__ h,
                               float* __restrict__ out_h, float* __restrict__ out_c)
{
    int idx = blockIdx.x * 256 + threadIdx.x;
    int r = idx >> 7, c = idx & 127;
    const float* g = gates + (size_t)r * G4;
    float gi = g[c]        + bih[c]        + bhh[c];
    float gf = g[128 + c]  + bih[128 + c]  + bhh[128 + c];
    float gg = g[256 + c]  + bih[256 + c]  + bhh[256 + c];
    float go = g[384 + c]  + bih[384 + c]  + bhh[384 + c];
    float cprev = lstm_c[idx] * masks[r];
    float cn = fsig(gf) * cprev + fsig(gi) * ftanh(gg);
    float hn = fsig(go) * ftanh(cn);
    h[idx] = hn;
    out_h[idx] = hn;
    out_c[idx] = cn;
}

// ---------------- persistent bidirectional GRU scan (MFMA, weights-stationary) --------
// identical structure to R10 (proven 200us); only U/V reads go through combined uv
// buffer with stride UVS.
__global__ __launch_bounds__(512, 2)
void gru_scan(const float* __restrict__ WhhF, const float* __restrict__ WhhB,
              const float* __restrict__ bhhF, const float* __restrict__ bhhB,
              const float* __restrict__ uv,
              const float* __restrict__ Whard,
              float* __restrict__ partF, float* __restrict__ partB)
{
    __shared__ __align__(16) unsigned short hHi[2][32][LDSW];
    __shared__ __align__(16) unsigned short hLo[2][32][LDSW];
    __shared__ float partLds[32][64][2];

    const int t = threadIdx.x;
    const int dir = blockIdx.x >> 7;
    const int blk = blockIdx.x & 127;
    const int r0 = blk * 32;
    const int bbx = r0 >> 6;
    const int n0 = r0 & 63;
    const int w  = t >> 6;
    const int l  = t & 63;
    const int li = l & 15;
    const int lg = l >> 4;
    const int cl = w * 16 + li;
    const bool pw = (w < 2);

    const float* Whh = dir ? WhhB : WhhF;
    const float* bhh = dir ? bhhB : bhhF;
    const float* U   = uv + dir * 768;
    const float* V   = uv + dir * 768 + 384;
    float* part      = dir ? partB : partF;

    f16x8 Bhi[3][4], Blo[3][4];
    #pragma unroll
    for (int g = 0; g < 3; ++g)
        #pragma unroll
        for (int kt = 0; kt < 4; ++kt) {
            const float* src = Whh + (size_t)(g * 128 + cl) * 128 + kt * 32 + lg * 8;
            #pragma unroll
            for (int j = 0; j < 8; ++j) {
                float wv = src[j];
                _Float16 hi = (_Float16)wv;
                _Float16 lo = (_Float16)((wv - (float)hi) * 1024.0f);
                Bhi[g][kt][j] = hi;
                Blo[g][kt][j] = lo;
            }
        }

    f16x8 Phi[4], Plo[4];
    if (pw) {
        #pragma unroll
        for (int kt = 0; kt < 4; ++kt) {
            #pragma unroll
            for (int j = 0; j < 8; ++j) {
                float wv = (li < 2) ? Whard[li * 256 + dir * 128 + kt * 32 + lg * 8 + j] : 0.0f;
                _Float16 hi = (_Float16)wv;
                _Float16 lo = (_Float16)((wv - (float)hi) * 1024.0f);
                Phi[kt][j] = hi;
                Plo[kt][j] = lo;
            }
        }
    }

    const float bh_r = bhh[cl];
    const float bh_z = bhh[128 + cl];
    const float bh_n = bhh[256 + cl];
    float u_r[8], u_z[8], u_n[8];
    #pragma unroll
    for (int rt = 0; rt < 2; ++rt)
        #pragma unroll
        for (int rg = 0; rg < 4; ++rg) {
            const int idx = rt * 4 + rg;
            const int R = r0 + rt * 16 + lg * 4 + rg;
            const float* Ur = U + (size_t)R * UVS;
            u_r[idx] = Ur[cl]       + bh_r;
            u_z[idx] = Ur[128 + cl] + bh_z;
            u_n[idx] = Ur[256 + cl] + bh_n;
        }

    const int vbase = bbx << 6;
    float v0r, v0z, v0n, v1r, v1z, v1n;
    {
        const int tt0 = dir ? (NM - 1) : 0;
        const float* Vr0 = V + (size_t)(vbase + tt0) * UVS;
        const float* Vr1 = V + (size_t)(vbase + tt0 + 1) * UVS;
        v0r = Vr0[cl]; v0z = Vr0[128 + cl]; v0n = Vr0[256 + cl];
        v1r = Vr1[cl]; v1z = Vr1[128 + cl]; v1n = Vr1[256 + cl];
    }

    for (int i = t; i < 2 * 32 * LDSW; i += 512) {
        (&hHi[0][0][0])[i] = 0;
        (&hLo[0][0][0])[i] = 0;
    }
    float hreg[8] = {0.f,0.f,0.f,0.f,0.f,0.f,0.f,0.f};

    int cur = 0;
    __syncthreads();

    for (int s = 0; s < NM; ++s) {
        const int tt = dir ? (NM - 1 - s) : s;

        float p0r, p0z, p0n, p1r, p1z, p1n;
        {
            const int sn = (s + 1 < NM) ? s + 1 : s;
            const int ttn = dir ? (NM - 1 - sn) : sn;
            const float* Vr0 = V + (size_t)(vbase + ttn) * UVS;
            const float* Vr1 = V + (size_t)(vbase + ttn + 1) * UVS;
            p0r = Vr0[cl]; p0z = Vr0[128 + cl]; p0n = Vr0[256 + cl];
            p1r = Vr1[cl]; p1z = Vr1[128 + cl]; p1n = Vr1[256 + cl];
        }

        f32x4 accA[3][2], accB[3][2], pA, pB;
        #pragma unroll
        for (int g = 0; g < 3; ++g)
            #pragma unroll
            for (int rt = 0; rt < 2; ++rt) {
                accA[g][rt] = (f32x4){0.f,0.f,0.f,0.f};
                accB[g][rt] = (f32x4){0.f,0.f,0.f,0.f};
            }
        pA = pB = (f32x4){0.f,0.f,0.f,0.f};

        #pragma unroll
        for (int kt = 0; kt < 4; ++kt) {
            f16x8 Ahi[2], Alo[2];
            const int koff = kt * 32 + lg * 8;
            #pragma unroll
            for (int rt = 0; rt < 2; ++rt) {
                const int arow = rt * 16 + li;
                Ahi[rt] = *(const f16x8*)&hHi[cur][arow][koff];
                Alo[rt] = *(const f16x8*)&hLo[cur][arow][koff];
            }
            #pragma unroll
            for (int g = 0; g < 3; ++g)
                #pragma unroll
                for (int rt = 0; rt < 2; ++rt) {
                    accA[g][rt] = __builtin_amdgcn_mfma_f32_16x16x32_f16(Ahi[rt], Bhi[g][kt], accA[g][rt], 0, 0, 0);
                    accB[g][rt] = __builtin_amdgcn_mfma_f32_16x16x32_f16(Alo[rt], Bhi[g][kt], accB[g][rt], 0, 0, 0);
                    accB[g][rt] = __builtin_amdgcn_mfma_f32_16x16x32_f16(Ahi[rt], Blo[g][kt], accB[g][rt], 0, 0, 0);
                }
            if (pw) {
                const f16x8 Aph = (w == 0) ? Ahi[0] : Ahi[1];
                const f16x8 Apl = (w == 0) ? Alo[0] : Alo[1];
                pA = __builtin_amdgcn_mfma_f32_16x16x32_f16(Aph, Phi[kt], pA, 0, 0, 0);
                pB = __builtin_amdgcn_mfma_f32_16x16x32_f16(Apl, Phi[kt], pB, 0, 0, 0);
                pB = __builtin_amdgcn_mfma_f32_16x16x32_f16(Aph, Plo[kt], pB, 0, 0, 0);
            }
        }

        if (pw && s > 0 && li < 2) {
            const int ttp = dir ? (tt + 1) : (tt - 1);
            #pragma unroll
            for (int rg = 0; rg < 4; ++rg) {
                const int row = w * 16 + lg * 4 + rg;
                partLds[row][ttp][li] = pA[rg] + pB[rg] * 9.765625e-4f;
            }
        }

        #pragma unroll
        for (int rt = 0; rt < 2; ++rt) {
            #pragma unroll
            for (int rg = 0; rg < 4; ++rg) {
                const int idx = rt * 4 + rg;
                const int row = rt * 16 + lg * 4 + rg;
                const int n = n0 + row;
                const bool up = (tt >= n);
                const float vr_ = up ? v1r : v0r;
                const float vz_ = up ? v1z : v0z;
                const float vn_ = up ? v1n : v0n;
                const float gr = fmaf(accB[0][rt][rg], 9.765625e-4f, accA[0][rt][rg]);
                const float gz = fmaf(accB[1][rt][rg], 9.765625e-4f, accA[1][rt][rg]);
                const float gn = fmaf(accB[2][rt][rg], 9.765625e-4f, accA[2][rt][rg]);
                const float rr  = fsig(u_r[idx] + vr_ + gr);
                const float zz  = fsig(u_z[idx] + vz_ + gz);
                const float nn2 = ftanh(u_n[idx] + vn_ + rr * gn);
                hreg[idx] = fmaf(zz, hreg[idx] - nn2, nn2);
            }
        }

        v0r = p0r; v0z = p0z; v0n = p0n;
        v1r = p1r; v1z = p1z; v1n = p1n;

        const int nxt = cur ^ 1;
        #pragma unroll
        for (int rt = 0; rt < 2; ++rt)
            #pragma unroll
            for (int rg = 0; rg < 4; ++rg) {
                const int row = rt * 16 + lg * 4 + rg;
                const float hn = hreg[rt * 4 + rg];
                _Float16 hi = (_Float16)hn;
                _Float16 lo = (_Float16)((hn - (float)hi) * 1024.0f);
                hHi[nxt][row][cl] = h2u(hi);
                hLo[nxt][row][cl] = h2u(lo);
            }
        cur = nxt;
        __syncthreads();
    }

    if (pw) {
        f32x4 qA = (f32x4){0.f,0.f,0.f,0.f}, qB = (f32x4){0.f,0.f,0.f,0.f};
        #pragma unroll
        for (int kt = 0; kt < 4; ++kt) {
            const int koff = kt * 32 + lg * 8;
            f16x8 Ah = *(const f16x8*)&hHi[cur][w * 16 + li][koff];
            f16x8 Al = *(const f16x8*)&hLo[cur][w * 16 + li][koff];
            qA = __builtin_amdgcn_mfma_f32_16x16x32_f16(Ah, Phi[kt], qA, 0, 0, 0);
            qB = __builtin_amdgcn_mfma_f32_16x16x32_f16(Al, Phi[kt], qB, 0, 0, 0);
            qB = __builtin_amdgcn_mfma_f32_16x16x32_f16(Ah, Plo[kt], qB, 0, 0, 0);
        }
        if (li < 2) {
            const int ttl = dir ? 0 : NM - 1;
            #pragma unroll
            for (int rg = 0; rg < 4; ++rg) {
                const int row = w * 16 + lg * 4 + rg;
                partLds[row][ttl][li] = qA[rg] + qB[rg] * 9.765625e-4f;
            }
        }
    }
    __syncthreads();

    {
        const int row = t >> 4;
        const int seg = t & 15;
        float* dst = part + (size_t)(r0 + row) * (NM * 2);
        #pragma unroll
        for (int k = 0; k < 4; ++k) {
            const int m = seg * 4 + k;
            if (m < NM) {
                float2 v = *(const float2*)&partLds[row][m][0];
                *(float2*)&dst[m * 2] = v;
            }
        }
    }
}

// ---------------- hard gate + soft attention + action head ----------------
__global__ __launch_bounds__(128)
void attn_final(const float* __restrict__ h, const float* __restrict__ qk,
                const float* __restrict__ partF, const float* __restrict__ partB,
                const float* __restrict__ bhard, const float* __restrict__ gum,
                const float* __restrict__ Wact, const float* __restrict__ bact,
                float* __restrict__ out_act, float* __restrict__ out_alp)
{
    const int r = blockIdx.x;
    const int bbx = r >> 6, n = r & 63;
    const int t = threadIdx.x;
    __shared__ float qsh[HH], wsh[NM], shh[HH], shx[HH];
    if (t < HH) { qsh[t] = qk[(size_t)r * QKS + t]; shh[t] = h[(size_t)r * HH + t]; }
    __syncthreads();
    if (t < 64) {
        float sc = -INFINITY;
        float hardv = 0.0f;
        if (t < NM) {
            const int idxm = t + (t >= n ? 1 : 0);
            const float4* kr = (const float4*)(qk + (size_t)((bbx << 6) + idxm) * QKS + 128);
            float s = 0.0f;
            #pragma unroll
            for (int j4 = 0; j4 < 32; ++j4) {
                float4 kv = kr[j4];
                float4 qv = *(const float4*)&qsh[j4 * 4];
                s += kv.x * qv.x + kv.y * qv.y + kv.z * qv.z + kv.w * qv.w;
            }
            sc = s * 0.088388347648318447f;   // 1/sqrt(128)
            const float2 pf = *(const float2*)(partF + ((size_t)r * NM + t) * 2);
            const float2 pb = *(const float2*)(partB + ((size_t)r * NM + t) * 2);
            const float2 gv = *(const float2*)(gum + ((size_t)r * NM + t) * 2);
            const float l0 = pf.x + pb.x + bhard[0] + gv.x;
            const float l1 = pf.y + pb.y + bhard[1] + gv.y;
            hardv = (l1 > l0) ? 1.0f : 0.0f;
        }
        float mx = sc;
        #pragma unroll
        for (int d = 32; d; d >>= 1) mx = fmaxf(mx, __shfl_xor(mx, d, 64));
        const float e = (t < NM) ? expf(sc - mx) : 0.0f;
        float sum = e;
        #pragma unroll
        for (int d = 32; d; d >>= 1) sum += __shfl_xor(sum, d, 64);
        if (t < NM) wsh[t] = hardv * e / sum;
    }
    __syncthreads();
    {
        const int j = t;
        float x = 0.0f;
        for (int m = 0; m < NM; ++m) {
            const int idxm = m + (m >= n ? 1 : 0);
            x = fmaf(wsh[m], h[(size_t)((bbx << 6) + idxm) * HH + j], x);
        }
        shx[j] = x;
    }
    __syncthreads();
    if (t < 16) {
        const float* wa = Wact + (size_t)t * 256;
        float acc = bact[t];
        #pragma unroll
        for (int j4 = 0; j4 < 32; ++j4) {
            float4 w1 = *(const float4*)&wa[j4 * 4];
            float4 hv = *(const float4*)&shh[j4 * 4];
            float4 w2 = *(const float4*)&wa[128 + j4 * 4];
            float4 xv = *(const float4*)&shx[j4 * 4];
            acc += w1.x * hv.x + w1.y * hv.y + w1.z * hv.z + w1.w * hv.w
                 + w2.x * xv.x + w2.y * xv.y + w2.z * xv.z + w2.w * xv.w;
        }
        float mx = acc; int am = t;
        #pragma unroll
        for (int d = 8; d; d >>= 1) {
            const float om = __shfl_xor(mx, d, 16);
            const int   oa = __shfl_xor(am, d, 16);
            if (om > mx || (om == mx && oa < am)) { mx = om; am = oa; }
        }
        const float e = expf(acc - mx);
        float sum = e;
        #pragma unroll
        for (int d = 8; d; d >>= 1) sum += __shfl_xor(sum, d, 16);
        if (t == 0) {
            out_act[r] = (float)am;
            out_alp[r] = -logf(sum);
        }
    }
}

// ---------------- launch ----------------
extern "C" void kernel_launch(void* const* d_in, const int* in_sizes, int n_in,
                              void* d_out, int out_size, void* d_ws, size_t ws_size,
                              hipStream_t stream)
{
    const float* obs    = (const float*)d_in[0];
    const float* lstm_h = (const float*)d_in[1];
    const float* lstm_c = (const float*)d_in[2];
    const float* masks  = (const float*)d_in[3];
    const float* W_enc  = (const float*)d_in[4];
    const float* b_enc  = (const float*)d_in[5];
    const float* lWih   = (const float*)d_in[6];
    const float* lWhh   = (const float*)d_in[7];
    const float* lbih   = (const float*)d_in[8];
    const float* lbhh   = (const float*)d_in[9];
    const float* gWihf  = (const float*)d_in[10];
    const float* gWhhf  = (const float*)d_in[11];
    const float* gbihf  = (const float*)d_in[12];
    const float* gbhhf  = (const float*)d_in[13];
    const float* gWihb  = (const float*)d_in[14];
    const float* gWhhb  = (const float*)d_in[15];
    const float* gbihb  = (const float*)d_in[16];
    const float* gbhhb  = (const float*)d_in[17];
    const float* Whard  = (const float*)d_in[18];
    const float* bhard  = (const float*)d_in[19];
    const float* Wq     = (const float*)d_in[20];
    const float* Wk     = (const float*)d_in[21];
    const float* Wact   = (const float*)d_in[22];
    const float* bact   = (const float*)d_in[23];
    const float* gum    = (const float*)d_in[24];

    float* W = (float*)d_ws;
    float* h     = W; W += (size_t)BN_ * HH;
    float* henc  = W; W += (size_t)BN_ * HH;
    float* gates = W; W += (size_t)BN_ * G4;
    float* uv    = W; W += (size_t)BN_ * UVS;
    float* partF = W; W += (size_t)BN_ * NM * 2;
    float* partB = W; W += (size_t)BN_ * NM * 2;
    float* qk    = W; W += (size_t)BN_ * QKS;

    float* out_f   = (float*)d_out;
    float* out_act = out_f;                       // 4096
    float* out_alp = out_act + BN_;               // 4096
    float* out_h   = out_alp + BN_;               // 4096*128
    float* out_c   = out_h + (size_t)BN_ * HH;    // 4096*128

    // henc = relu(obs @ W_enc^T + b_enc)
    gemm_mfma<false, true, false><<<dim3(2, BN_ / 64), 256, 0, stream>>>(
        obs, OBS_, nullptr, 0, nullptr,
        W_enc, nullptr, nullptr, nullptr, nullptr, OBS_, 2,
        b_enc, nullptr, nullptr, nullptr, henc, HH);
    // gates = henc @ lWih^T + (lstm_h*masks) @ lWhh^T
    gemm_mfma<true, false, true><<<dim3(8, BN_ / 64), 256, 0, stream>>>(
        henc, HH, lstm_h, HH, masks,
        lWih, nullptr, nullptr, nullptr, lWhh, HH, 8,
        nullptr, nullptr, nullptr, nullptr, gates, G4);
    lstm_pointwise<<<BN_ * HH / 256, 256, 0, stream>>>(gates, lbih, lbhh, lstm_c, masks,
                                                       h, out_h, out_c);
    // uv = [Uf | Vf | Ub | Vb], 4 segments of 384 cols (6 tiles each)
    gemm_mfma<false, false, false><<<dim3(24, BN_ / 64), 256, 0, stream>>>(
        h, HH, nullptr, 0, nullptr,
        gWihf, gWihf + HH, gWihb, gWihb + HH, nullptr, 2 * HH, 6,
        gbihf, nullptr, gbihb, nullptr, uv, UVS);
    // qk = [q | k], 2 segments of 128 cols (2 tiles each)
    gemm_mfma<false, false, false><<<dim3(4, BN_ / 64), 256, 0, stream>>>(
        h, HH, nullptr, 0, nullptr,
        Wq, Wk, nullptr, nullptr, nullptr, HH, 2,
        nullptr, nullptr, nullptr, nullptr, qk, QKS);
    gru_scan<<<256, 512, 0, stream>>>(gWhhf, gWhhb, gbhhf, gbhhb, uv,
                                      Whard, partF, partB);
    attn_final<<<BN_, 128, 0, stream>>>(h, qk, partF, partB, bhard, gum,
                                        Wact, bact, out_act, out_alp);
}

// Round 12
// 231.940 us; speedup vs baseline: 3.1641x; 1.0945x over previous
//
#include <hip/hip_runtime.h>
#include <hip/hip_bf16.h>
#include <math.h>

#define BB   64
#define NN   64
#define HH   128
#define OBS_ 128
#define AA   16
#define BN_  4096
#define NM   63
#define G3   384
#define G4   512
#define UVS  1792      // combined U|V|q|k row stride (1536 uv + 256 qk)
#define LDSW 136       // ushorts/row

typedef _Float16 f16x8 __attribute__((ext_vector_type(8)));
typedef float    f32x4 __attribute__((ext_vector_type(4)));

// fast device transcendentals (v_exp_f32 / v_rcp_f32, ~2-3 ulp)
__device__ __forceinline__ float fsig(float x) {
    return __builtin_amdgcn_rcpf(1.0f + __builtin_amdgcn_exp2f(-1.4426950408889634f * x));
}
__device__ __forceinline__ float ftanh(float x) {
    return 1.0f - 2.0f * __builtin_amdgcn_rcpf(1.0f + __builtin_amdgcn_exp2f(2.8853900817779268f * x));
}

__device__ __forceinline__ unsigned short h2u(_Float16 h) {
    union { _Float16 f; unsigned short u; } cv; cv.f = h; return cv.u;
}

// ---------------- MFMA GEMM: C = A@B^T (+ A2@B2^T) with split-f16 precision ----------
// 64x64 tile, 256 threads = 4 waves; wave w owns cols [w*16, w*16+16).
// N segmented: segs 0-3 have tilesPerSeg tiles (ldb), segs 4-5 have 2 tiles (ldb2).
template<bool DUAL, bool RELU, bool RMASK>
__global__ __launch_bounds__(256)
void gemm_mfma(const float* __restrict__ A, int lda,
               const float* __restrict__ A2, int lda2,
               const float* __restrict__ rmask,
               const float* __restrict__ Bs0, const float* __restrict__ Bs1,
               const float* __restrict__ Bs2, const float* __restrict__ Bs3,
               const float* __restrict__ Bs4, const float* __restrict__ Bs5,
               const float* __restrict__ Bd, int ldb, int ldb2, int tilesPerSeg,
               const float* __restrict__ bias0, const float* __restrict__ bias2,
               float* __restrict__ C, int ldc)
{
    __shared__ __align__(16) unsigned short aHi[64][LDSW];
    __shared__ __align__(16) unsigned short aLo[64][LDSW];

    const int t = threadIdx.x;
    const int w = t >> 6, l = t & 63, li = l & 15, lg = l >> 4;
    const int bx = blockIdx.x, by = blockIdx.y;
    int seg, tIdx;
    if (bx < 4 * tilesPerSeg) { seg = bx / tilesPerSeg; tIdx = bx % tilesPerSeg; }
    else { const int r2 = bx - 4 * tilesPerSeg; seg = 4 + (r2 >> 1); tIdx = r2 & 1; }
    const int cts = tIdx * 64;
    const float* Bseg = seg == 0 ? Bs0 : seg == 1 ? Bs1 : seg == 2 ? Bs2
                       : seg == 3 ? Bs3 : seg == 4 ? Bs4 : Bs5;
    const float* biasSeg = seg == 0 ? bias0 : seg == 2 ? bias2 : nullptr;
    const int ldbs = (seg < 4) ? ldb : ldb2;
    const int row0 = by * 64;
    const int cl = w * 16 + li;

    f32x4 accA[4], accB[4];
    #pragma unroll
    for (int rt = 0; rt < 4; ++rt) {
        accA[rt] = (f32x4){0.f,0.f,0.f,0.f};
        accB[rt] = (f32x4){0.f,0.f,0.f,0.f};
    }

    const int npass = DUAL ? 2 : 1;
    for (int pass = 0; pass < npass; ++pass) {
        const float* Ap = pass ? A2 : A;
        const int ldap = pass ? lda2 : lda;
        __syncthreads();                     // guard LDS reuse across passes
        {   // stage A tile 64x128 as split-f16: thread -> row t>>2, 32 k-values
            const int ar = t >> 2, kof = (t & 3) * 32;
            const float* src = Ap + (size_t)(row0 + ar) * ldap + kof;
            float mk = 1.0f;
            if (RMASK && pass == 1) mk = rmask[row0 + ar];
            #pragma unroll
            for (int q = 0; q < 8; ++q) {
                float4 v = *(const float4*)(src + q * 4);
                if (RMASK && pass == 1) { v.x *= mk; v.y *= mk; v.z *= mk; v.w *= mk; }
                float vv[4] = {v.x, v.y, v.z, v.w};
                unsigned int hi01, hi23, lo01, lo23;
                {
                    _Float16 h0 = (_Float16)vv[0], h1 = (_Float16)vv[1];
                    _Float16 h2 = (_Float16)vv[2], h3 = (_Float16)vv[3];
                    _Float16 l0 = (_Float16)((vv[0] - (float)h0) * 1024.0f);
                    _Float16 l1 = (_Float16)((vv[1] - (float)h1) * 1024.0f);
                    _Float16 l2 = (_Float16)((vv[2] - (float)h2) * 1024.0f);
                    _Float16 l3 = (_Float16)((vv[3] - (float)h3) * 1024.0f);
                    hi01 = (unsigned int)h2u(h0) | ((unsigned int)h2u(h1) << 16);
                    hi23 = (unsigned int)h2u(h2) | ((unsigned int)h2u(h3) << 16);
                    lo01 = (unsigned int)h2u(l0) | ((unsigned int)h2u(l1) << 16);
                    lo23 = (unsigned int)h2u(l2) | ((unsigned int)h2u(l3) << 16);
                }
                *(uint2*)&aHi[ar][kof + q * 4] = make_uint2(hi01, hi23);
                *(uint2*)&aLo[ar][kof + q * 4] = make_uint2(lo01, lo23);
            }
        }
        // B fragments for this pass: col cts+cl, k = kt*32 + lg*8 + j
        const float* Bp = (DUAL && pass) ? Bd : Bseg;
        const int ldbp = (DUAL && pass) ? ldb : ldbs;
        f16x8 bhi[4], blo[4];
        #pragma unroll
        for (int kt = 0; kt < 4; ++kt) {
            const float* srcB = Bp + (size_t)(cts + cl) * ldbp + kt * 32 + lg * 8;
            #pragma unroll
            for (int j = 0; j < 8; ++j) {
                float wv = srcB[j];
                _Float16 hi = (_Float16)wv;
                _Float16 lo = (_Float16)((wv - (float)hi) * 1024.0f);
                bhi[kt][j] = hi;
                blo[kt][j] = lo;
            }
        }
        __syncthreads();
        #pragma unroll
        for (int kt = 0; kt < 4; ++kt) {
            const int koff = kt * 32 + lg * 8;
            #pragma unroll
            for (int rt = 0; rt < 4; ++rt) {
                f16x8 ah = *(const f16x8*)&aHi[rt * 16 + li][koff];
                f16x8 al = *(const f16x8*)&aLo[rt * 16 + li][koff];
                accA[rt] = __builtin_amdgcn_mfma_f32_16x16x32_f16(ah, bhi[kt], accA[rt], 0, 0, 0);
                accB[rt] = __builtin_amdgcn_mfma_f32_16x16x32_f16(al, bhi[kt], accB[rt], 0, 0, 0);
                accB[rt] = __builtin_amdgcn_mfma_f32_16x16x32_f16(ah, blo[kt], accB[rt], 0, 0, 0);
            }
        }
    }

    const float bv = biasSeg ? biasSeg[cts + cl] : 0.0f;
    const int gcol = bx * 64 + cl;
    #pragma unroll
    for (int rt = 0; rt < 4; ++rt)
        #pragma unroll
        for (int rg = 0; rg < 4; ++rg) {
            float x = fmaf(accB[rt][rg], 9.765625e-4f, accA[rt][rg]) + bv;
            if (RELU) x = fmaxf(x, 0.0f);
            const int r = row0 + rt * 16 + lg * 4 + rg;
            C[(size_t)r * ldc + gcol] = x;
        }
}

__global__ void lstm_pointwise(const float* __restrict__ gates,
                               const float* __restrict__ bih, const float* __restrict__ bhh,
                               const float* __restrict__ lstm_c, const float* __restrict__ masks,
                               float* __restrict__ h,
                               float* __restrict__ out_h, float* __restrict__ out_c)
{
    int idx = blockIdx.x * 256 + threadIdx.x;
    int r = idx >> 7, c = idx & 127;
    const float* g = gates + (size_t)r * G4;
    float gi = g[c]        + bih[c]        + bhh[c];
    float gf = g[128 + c]  + bih[128 + c]  + bhh[128 + c];
    float gg = g[256 + c]  + bih[256 + c]  + bhh[256 + c];
    float go = g[384 + c]  + bih[384 + c]  + bhh[384 + c];
    float cprev = lstm_c[idx] * masks[r];
    float cn = fsig(gf) * cprev + fsig(gi) * ftanh(gg);
    float hn = fsig(go) * ftanh(cn);
    h[idx] = hn;
    out_h[idx] = hn;
    out_c[idx] = cn;
}

// ---------------- persistent bidirectional GRU scan (MFMA, weights-stationary) --------
// 256 blocks, 512 threads = 8 waves, 32 rows/block. Step split into rt0/rt1 half-tiles
// so epilogue VALU of half 0 overlaps MFMA of half 1 (phase de-lockstep).
__global__ __launch_bounds__(512, 2)
void gru_scan(const float* __restrict__ WhhF, const float* __restrict__ WhhB,
              const float* __restrict__ bhhF, const float* __restrict__ bhhB,
              const float* __restrict__ uvqk,
              const float* __restrict__ Whard,
              float* __restrict__ partF, float* __restrict__ partB)
{
    __shared__ __align__(16) unsigned short hHi[2][32][LDSW];
    __shared__ __align__(16) unsigned short hLo[2][32][LDSW];
    __shared__ float partLds[32][64][2];

    const int t = threadIdx.x;
    const int dir = blockIdx.x >> 7;
    const int blk = blockIdx.x & 127;
    const int r0 = blk * 32;
    const int bbx = r0 >> 6;
    const int n0 = r0 & 63;
    const int w  = t >> 6;
    const int l  = t & 63;
    const int li = l & 15;
    const int lg = l >> 4;
    const int cl = w * 16 + li;

    const float* Whh = dir ? WhhB : WhhF;
    const float* bhh = dir ? bhhB : bhhF;
    const float* U   = uvqk + dir * 768;
    const float* V   = uvqk + dir * 768 + 384;
    float* part      = dir ? partB : partF;

    f16x8 Bhi[3][4], Blo[3][4];
    #pragma unroll
    for (int g = 0; g < 3; ++g)
        #pragma unroll
        for (int kt = 0; kt < 4; ++kt) {
            const float* src = Whh + (size_t)(g * 128 + cl) * 128 + kt * 32 + lg * 8;
            #pragma unroll
            for (int j = 0; j < 8; ++j) {
                float wv = src[j];
                _Float16 hi = (_Float16)wv;
                _Float16 lo = (_Float16)((wv - (float)hi) * 1024.0f);
                Bhi[g][kt][j] = hi;
                Blo[g][kt][j] = lo;
            }
        }

    const bool pw = (w < 2);
    f16x8 Phi[4], Plo[4];
    if (pw) {
        #pragma unroll
        for (int kt = 0; kt < 4; ++kt) {
            #pragma unroll
            for (int j = 0; j < 8; ++j) {
                float wv = (li < 2) ? Whard[li * 256 + dir * 128 + kt * 32 + lg * 8 + j] : 0.0f;
                _Float16 hi = (_Float16)wv;
                _Float16 lo = (_Float16)((wv - (float)hi) * 1024.0f);
                Phi[kt][j] = hi;
                Plo[kt][j] = lo;
            }
        }
    }

    const float bh_r = bhh[cl];
    const float bh_z = bhh[128 + cl];
    const float bh_n = bhh[256 + cl];
    float u_r[8], u_z[8], u_n[8];
    #pragma unroll
    for (int rt = 0; rt < 2; ++rt)
        #pragma unroll
        for (int rg = 0; rg < 4; ++rg) {
            const int idx = rt * 4 + rg;
            const int R = r0 + rt * 16 + lg * 4 + rg;
            const float* Ur = U + (size_t)R * UVS;
            u_r[idx] = Ur[cl]       + bh_r;
            u_z[idx] = Ur[128 + cl] + bh_z;
            u_n[idx] = Ur[256 + cl] + bh_n;
        }

    const int vbase = bbx << 6;
    float v0r, v0z, v0n, v1r, v1z, v1n;
    {
        const int tt0 = dir ? (NM - 1) : 0;
        const float* Vr0 = V + (size_t)(vbase + tt0) * UVS;
        const float* Vr1 = V + (size_t)(vbase + tt0 + 1) * UVS;
        v0r = Vr0[cl]; v0z = Vr0[128 + cl]; v0n = Vr0[256 + cl];
        v1r = Vr1[cl]; v1z = Vr1[128 + cl]; v1n = Vr1[256 + cl];
    }

    for (int i = t; i < 2 * 32 * LDSW; i += 512) {
        (&hHi[0][0][0])[i] = 0;
        (&hLo[0][0][0])[i] = 0;
    }
    float hreg[8] = {0.f,0.f,0.f,0.f,0.f,0.f,0.f,0.f};

    int cur = 0;
    __syncthreads();

    for (int s = 0; s < NM; ++s) {
        const int tt = dir ? (NM - 1 - s) : s;
        const int nxt = cur ^ 1;

        // next-step V prefetch (hides under MFMA)
        float p0r, p0z, p0n, p1r, p1z, p1n;
        {
            const int sn = (s + 1 < NM) ? s + 1 : s;
            const int ttn = dir ? (NM - 1 - sn) : sn;
            const float* Vr0 = V + (size_t)(vbase + ttn) * UVS;
            const float* Vr1 = V + (size_t)(vbase + ttn + 1) * UVS;
            p0r = Vr0[cl]; p0z = Vr0[128 + cl]; p0n = Vr0[256 + cl];
            p1r = Vr1[cl]; p1z = Vr1[128 + cl]; p1n = Vr1[256 + cl];
        }

        // ---------- half-tile rt = 0 (rows 0-15): MFMA ----------
        f32x4 a0[3], b0[3], pA, pB;
        a0[0] = a0[1] = a0[2] = (f32x4){0.f,0.f,0.f,0.f};
        b0[0] = b0[1] = b0[2] = (f32x4){0.f,0.f,0.f,0.f};
        pA = pB = (f32x4){0.f,0.f,0.f,0.f};
        #pragma unroll
        for (int kt = 0; kt < 4; ++kt) {
            const int koff = kt * 32 + lg * 8;
            f16x8 Ah = *(const f16x8*)&hHi[cur][li][koff];
            f16x8 Al = *(const f16x8*)&hLo[cur][li][koff];
            #pragma unroll
            for (int g = 0; g < 3; ++g) {
                a0[g] = __builtin_amdgcn_mfma_f32_16x16x32_f16(Ah, Bhi[g][kt], a0[g], 0, 0, 0);
                b0[g] = __builtin_amdgcn_mfma_f32_16x16x32_f16(Al, Bhi[g][kt], b0[g], 0, 0, 0);
                b0[g] = __builtin_amdgcn_mfma_f32_16x16x32_f16(Ah, Blo[g][kt], b0[g], 0, 0, 0);
            }
            if (w == 0) {
                pA = __builtin_amdgcn_mfma_f32_16x16x32_f16(Ah, Phi[kt], pA, 0, 0, 0);
                pB = __builtin_amdgcn_mfma_f32_16x16x32_f16(Al, Phi[kt], pB, 0, 0, 0);
                pB = __builtin_amdgcn_mfma_f32_16x16x32_f16(Ah, Plo[kt], pB, 0, 0, 0);
            }
        }
        // epilogue rt0 (overlaps with rt1 MFMA below)
        #pragma unroll
        for (int rg = 0; rg < 4; ++rg) {
            const int row = lg * 4 + rg;
            const bool up = (tt >= n0 + row);
            const float gr = fmaf(b0[0][rg], 9.765625e-4f, a0[0][rg]);
            const float gz = fmaf(b0[1][rg], 9.765625e-4f, a0[1][rg]);
            const float gn = fmaf(b0[2][rg], 9.765625e-4f, a0[2][rg]);
            const float rr  = fsig(u_r[rg] + (up ? v1r : v0r) + gr);
            const float zz  = fsig(u_z[rg] + (up ? v1z : v0z) + gz);
            const float nn2 = ftanh(u_n[rg] + (up ? v1n : v0n) + rr * gn);
            const float hn = fmaf(zz, hreg[rg] - nn2, nn2);
            hreg[rg] = hn;
            _Float16 hi = (_Float16)hn;
            _Float16 lo = (_Float16)((hn - (float)hi) * 1024.0f);
            hHi[nxt][row][cl] = h2u(hi);
            hLo[nxt][row][cl] = h2u(lo);
        }
        if (w == 0 && s > 0 && li < 2) {
            const int ttp = dir ? (tt + 1) : (tt - 1);
            #pragma unroll
            for (int rg = 0; rg < 4; ++rg)
                partLds[lg * 4 + rg][ttp][li] = pA[rg] + pB[rg] * 9.765625e-4f;
        }

        // ---------- half-tile rt = 1 (rows 16-31): MFMA ----------
        f32x4 a1[3], b1[3];
        a1[0] = a1[1] = a1[2] = (f32x4){0.f,0.f,0.f,0.f};
        b1[0] = b1[1] = b1[2] = (f32x4){0.f,0.f,0.f,0.f};
        f32x4 qA, qB;
        qA = qB = (f32x4){0.f,0.f,0.f,0.f};
        #pragma unroll
        for (int kt = 0; kt < 4; ++kt) {
            const int koff = kt * 32 + lg * 8;
            f16x8 Ah = *(const f16x8*)&hHi[cur][16 + li][koff];
            f16x8 Al = *(const f16x8*)&hLo[cur][16 + li][koff];
            #pragma unroll
            for (int g = 0; g < 3; ++g) {
                a1[g] = __builtin_amdgcn_mfma_f32_16x16x32_f16(Ah, Bhi[g][kt], a1[g], 0, 0, 0);
                b1[g] = __builtin_amdgcn_mfma_f32_16x16x32_f16(Al, Bhi[g][kt], b1[g], 0, 0, 0);
                b1[g] = __builtin_amdgcn_mfma_f32_16x16x32_f16(Ah, Blo[g][kt], b1[g], 0, 0, 0);
            }
            if (w == 1) {
                qA = __builtin_amdgcn_mfma_f32_16x16x32_f16(Ah, Phi[kt], qA, 0, 0, 0);
                qB = __builtin_amdgcn_mfma_f32_16x16x32_f16(Al, Phi[kt], qB, 0, 0, 0);
                qB = __builtin_amdgcn_mfma_f32_16x16x32_f16(Ah, Plo[kt], qB, 0, 0, 0);
            }
        }
        // epilogue rt1
        #pragma unroll
        for (int rg = 0; rg < 4; ++rg) {
            const int row = 16 + lg * 4 + rg;
            const int idx = 4 + rg;
            const bool up = (tt >= n0 + row);
            const float gr = fmaf(b1[0][rg], 9.765625e-4f, a1[0][rg]);
            const float gz = fmaf(b1[1][rg], 9.765625e-4f, a1[1][rg]);
            const float gn = fmaf(b1[2][rg], 9.765625e-4f, a1[2][rg]);
            const float rr  = fsig(u_r[idx] + (up ? v1r : v0r) + gr);
            const float zz  = fsig(u_z[idx] + (up ? v1z : v0z) + gz);
            const float nn2 = ftanh(u_n[idx] + (up ? v1n : v0n) + rr * gn);
            const float hn = fmaf(zz, hreg[idx] - nn2, nn2);
            hreg[idx] = hn;
            _Float16 hi = (_Float16)hn;
            _Float16 lo = (_Float16)((hn - (float)hi) * 1024.0f);
            hHi[nxt][row][cl] = h2u(hi);
            hLo[nxt][row][cl] = h2u(lo);
        }
        if (w == 1 && s > 0 && li < 2) {
            const int ttp = dir ? (tt + 1) : (tt - 1);
            #pragma unroll
            for (int rg = 0; rg < 4; ++rg)
                partLds[16 + lg * 4 + rg][ttp][li] = qA[rg] + qB[rg] * 9.765625e-4f;
        }

        v0r = p0r; v0z = p0z; v0n = p0n;
        v1r = p1r; v1z = p1z; v1n = p1n;
        cur = nxt;
        __syncthreads();
    }

    // final-step W_hard logits (h_{last} sits in buf[cur])
    if (pw) {
        f32x4 qA = (f32x4){0.f,0.f,0.f,0.f}, qB = (f32x4){0.f,0.f,0.f,0.f};
        #pragma unroll
        for (int kt = 0; kt < 4; ++kt) {
            const int koff = kt * 32 + lg * 8;
            f16x8 Ah = *(const f16x8*)&hHi[cur][w * 16 + li][koff];
            f16x8 Al = *(const f16x8*)&hLo[cur][w * 16 + li][koff];
            qA = __builtin_amdgcn_mfma_f32_16x16x32_f16(Ah, Phi[kt], qA, 0, 0, 0);
            qB = __builtin_amdgcn_mfma_f32_16x16x32_f16(Al, Phi[kt], qB, 0, 0, 0);
            qB = __builtin_amdgcn_mfma_f32_16x16x32_f16(Ah, Plo[kt], qB, 0, 0, 0);
        }
        if (li < 2) {
            const int ttl = dir ? 0 : NM - 1;
            #pragma unroll
            for (int rg = 0; rg < 4; ++rg) {
                const int row = w * 16 + lg * 4 + rg;
                partLds[row][ttl][li] = qA[rg] + qB[rg] * 9.765625e-4f;
            }
        }
    }
    __syncthreads();

    {
        const int row = t >> 4;
        const int seg = t & 15;
        float* dst = part + (size_t)(r0 + row) * (NM * 2);
        #pragma unroll
        for (int k = 0; k < 4; ++k) {
            const int m = seg * 4 + k;
            if (m < NM) {
                float2 v = *(const float2*)&partLds[row][m][0];
                *(float2*)&dst[m * 2] = v;
            }
        }
    }
}

// ---------------- hard gate + soft attention + action head ----------------
__global__ __launch_bounds__(128)
void attn_final(const float* __restrict__ h, const float* __restrict__ qk,
                const float* __restrict__ partF, const float* __restrict__ partB,
                const float* __restrict__ bhard, const float* __restrict__ gum,
                const float* __restrict__ Wact, const float* __restrict__ bact,
                float* __restrict__ out_act, float* __restrict__ out_alp)
{
    const int r = blockIdx.x;
    const int bbx = r >> 6, n = r & 63;
    const int t = threadIdx.x;
    __shared__ float qsh[HH], wsh[NM], shh[HH], shx[HH];
    if (t < HH) { qsh[t] = qk[(size_t)r * UVS + t]; shh[t] = h[(size_t)r * HH + t]; }
    __syncthreads();
    if (t < 64) {
        float sc = -INFINITY;
        float hardv = 0.0f;
        if (t < NM) {
            const int idxm = t + (t >= n ? 1 : 0);
            const float4* kr = (const float4*)(qk + (size_t)((bbx << 6) + idxm) * UVS + 128);
            float s = 0.0f;
            #pragma unroll
            for (int j4 = 0; j4 < 32; ++j4) {
                float4 kv = kr[j4];
                float4 qv = *(const float4*)&qsh[j4 * 4];
                s += kv.x * qv.x + kv.y * qv.y + kv.z * qv.z + kv.w * qv.w;
            }
            sc = s * 0.088388347648318447f;   // 1/sqrt(128)
            const float2 pf = *(const float2*)(partF + ((size_t)r * NM + t) * 2);
            const float2 pb = *(const float2*)(partB + ((size_t)r * NM + t) * 2);
            const float2 gv = *(const float2*)(gum + ((size_t)r * NM + t) * 2);
            const float l0 = pf.x + pb.x + bhard[0] + gv.x;
            const float l1 = pf.y + pb.y + bhard[1] + gv.y;
            hardv = (l1 > l0) ? 1.0f : 0.0f;
        }
        float mx = sc;
        #pragma unroll
        for (int d = 32; d; d >>= 1) mx = fmaxf(mx, __shfl_xor(mx, d, 64));
        const float e = (t < NM) ? expf(sc - mx) : 0.0f;
        float sum = e;
        #pragma unroll
        for (int d = 32; d; d >>= 1) sum += __shfl_xor(sum, d, 64);
        if (t < NM) wsh[t] = hardv * e / sum;
    }
    __syncthreads();
    {
        const int j = t;
        float x = 0.0f;
        for (int m = 0; m < NM; ++m) {
            const int idxm = m + (m >= n ? 1 : 0);
            x = fmaf(wsh[m], h[(size_t)((bbx << 6) + idxm) * HH + j], x);
        }
        shx[j] = x;
    }
    __syncthreads();
    if (t < 16) {
        const float* wa = Wact + (size_t)t * 256;
        float acc = bact[t];
        #pragma unroll
        for (int j4 = 0; j4 < 32; ++j4) {
            float4 w1 = *(const float4*)&wa[j4 * 4];
            float4 hv = *(const float4*)&shh[j4 * 4];
            float4 w2 = *(const float4*)&wa[128 + j4 * 4];
            float4 xv = *(const float4*)&shx[j4 * 4];
            acc += w1.x * hv.x + w1.y * hv.y + w1.z * hv.z + w1.w * hv.w
                 + w2.x * xv.x + w2.y * xv.y + w2.z * xv.z + w2.w * xv.w;
        }
        float mx = acc; int am = t;
        #pragma unroll
        for (int d = 8; d; d >>= 1) {
            const float om = __shfl_xor(mx, d, 16);
            const int   oa = __shfl_xor(am, d, 16);
            if (om > mx || (om == mx && oa < am)) { mx = om; am = oa; }
        }
        const float e = expf(acc - mx);
        float sum = e;
        #pragma unroll
        for (int d = 8; d; d >>= 1) sum += __shfl_xor(sum, d, 16);
        if (t == 0) {
            out_act[r] = (float)am;
            out_alp[r] = -logf(sum);
        }
    }
}

// ---------------- launch ----------------
extern "C" void kernel_launch(void* const* d_in, const int* in_sizes, int n_in,
                              void* d_out, int out_size, void* d_ws, size_t ws_size,
                              hipStream_t stream)
{
    const float* obs    = (const float*)d_in[0];
    const float* lstm_h = (const float*)d_in[1];
    const float* lstm_c = (const float*)d_in[2];
    const float* masks  = (const float*)d_in[3];
    const float* W_enc  = (const float*)d_in[4];
    const float* b_enc  = (const float*)d_in[5];
    const float* lWih   = (const float*)d_in[6];
    const float* lWhh   = (const float*)d_in[7];
    const float* lbih   = (const float*)d_in[8];
    const float* lbhh   = (const float*)d_in[9];
    const float* gWihf  = (const float*)d_in[10];
    const float* gWhhf  = (const float*)d_in[11];
    const float* gbihf  = (const float*)d_in[12];
    const float* gbhhf  = (const float*)d_in[13];
    const float* gWihb  = (const float*)d_in[14];
    const float* gWhhb  = (const float*)d_in[15];
    const float* gbihb  = (const float*)d_in[16];
    const float* gbhhb  = (const float*)d_in[17];
    const float* Whard  = (const float*)d_in[18];
    const float* bhard  = (const float*)d_in[19];
    const float* Wq     = (const float*)d_in[20];
    const float* Wk     = (const float*)d_in[21];
    const float* Wact   = (const float*)d_in[22];
    const float* bact   = (const float*)d_in[23];
    const float* gum    = (const float*)d_in[24];

    float* W = (float*)d_ws;
    float* h     = W; W += (size_t)BN_ * HH;
    float* henc  = W; W += (size_t)BN_ * HH;
    float* gates = W; W += (size_t)BN_ * G4;
    float* uvqk  = W; W += (size_t)BN_ * UVS;
    float* partF = W; W += (size_t)BN_ * NM * 2;
    float* partB = W; W += (size_t)BN_ * NM * 2;

    float* out_f   = (float*)d_out;
    float* out_act = out_f;                       // 4096
    float* out_alp = out_act + BN_;               // 4096
    float* out_h   = out_alp + BN_;               // 4096*128
    float* out_c   = out_h + (size_t)BN_ * HH;    // 4096*128

    // henc = relu(obs @ W_enc^T + b_enc)
    gemm_mfma<false, true, false><<<dim3(2, BN_ / 64), 256, 0, stream>>>(
        obs, OBS_, nullptr, 0, nullptr,
        W_enc, nullptr, nullptr, nullptr, nullptr, nullptr, nullptr,
        OBS_, OBS_, 2, b_enc, nullptr, henc, HH);
    // gates = henc @ lWih^T + (lstm_h*masks) @ lWhh^T
    gemm_mfma<true, false, true><<<dim3(8, BN_ / 64), 256, 0, stream>>>(
        henc, HH, lstm_h, HH, masks,
        lWih, nullptr, nullptr, nullptr, nullptr, nullptr, lWhh,
        HH, HH, 8, nullptr, nullptr, gates, G4);
    lstm_pointwise<<<BN_ * HH / 256, 256, 0, stream>>>(gates, lbih, lbhh, lstm_c, masks,
                                                       h, out_h, out_c);
    // uvqk = [Uf | Vf | Ub | Vb | q | k]: segs 0-3 = 6 tiles (ldb 256), segs 4-5 = 2 tiles (ldb 128)
    gemm_mfma<false, false, false><<<dim3(28, BN_ / 64), 256, 0, stream>>>(
        h, HH, nullptr, 0, nullptr,
        gWihf, gWihf + HH, gWihb, gWihb + HH, Wq, Wk, nullptr,
        2 * HH, HH, 6, gbihf, gbihb, uvqk, UVS);
    gru_scan<<<256, 512, 0, stream>>>(gWhhf, gWhhb, gbhhf, gbhhb, uvqk,
                                      Whard, partF, partB);
    attn_final<<<BN_, 128, 0, stream>>>(h, uvqk + 1536, partF, partB, bhard, gum,
                                        Wact, bact, out_act, out_alp);
}